// Round 2
// baseline (342.128 us; speedup 1.0000x reference)
//
#include <hip/hip_runtime.h>
#include <hip/hip_bf16.h>
#include <cmath>

#define T_SEQ 2048
#define D_MODEL 1024
#define NHEAD 16
#define DK 64

typedef short bf16x8 __attribute__((ext_vector_type(8)));
typedef float f32x4 __attribute__((ext_vector_type(4)));

// RNE float -> bf16 (finite inputs only)
__device__ __forceinline__ short f2b(float f) {
    unsigned u = __builtin_bit_cast(unsigned, f);
    unsigned r = (u + 0x7FFFu + ((u >> 16) & 1u)) >> 16;
    return (short)r;
}

// ---------------- fp32 -> bf16 convert (vectorized) ----------------
__global__ __launch_bounds__(256) void cvt_bf16(const float* __restrict__ in,
                                                short* __restrict__ out, int n8) {
    int i = blockIdx.x * blockDim.x + threadIdx.x;
    if (i >= n8) return;
    float4 a = reinterpret_cast<const float4*>(in)[2 * i];
    float4 b = reinterpret_cast<const float4*>(in)[2 * i + 1];
    bf16x8 v;
    v[0] = f2b(a.x); v[1] = f2b(a.y); v[2] = f2b(a.z); v[3] = f2b(a.w);
    v[4] = f2b(b.x); v[5] = f2b(b.y); v[6] = f2b(b.z); v[7] = f2b(b.w);
    reinterpret_cast<bf16x8*>(out)[i] = v;
}

// ---------------- RoPE cos/sin tables: (B*T, 32) ----------------
__global__ __launch_bounds__(256) void rope_table(const int* __restrict__ pos,
                                                  float* __restrict__ ct,
                                                  float* __restrict__ st) {
    int i = blockIdx.x * blockDim.x + threadIdx.x;   // B*T*32 threads
    int bt = i >> 5, n = i & 31;
    float p = (float)pos[bt];
    float invf = expf((float)n * (-2.0f / (float)DK) * 9.210340371976184f);
    float ang = p * invf;
    float s, c;
    sincosf(ang, &s, &c);
    ct[i] = c; st[i] = s;
}

// ---------------- GEMM1: qkv = x * W_qkv^T, fused RoPE, scatter ----------------
__global__ __launch_bounds__(256) void gemm_qkv(const short* __restrict__ xb,
                                                const short* __restrict__ wb,
                                                const float* __restrict__ ct,
                                                const float* __restrict__ st,
                                                short* __restrict__ Qo,
                                                short* __restrict__ Ko,
                                                short* __restrict__ Vt) {
    __shared__ short As[64][40];
    __shared__ short Bs[64][40];
    const int bm = blockIdx.y * 64, bn = blockIdx.x * 64;
    const int tid = threadIdx.x;
    const int w = tid >> 6, l = tid & 63, lg = l >> 4, li = l & 15;
    const int srow = tid >> 2, scg = (tid & 3) * 8;

    f32x4 zero = {0.f, 0.f, 0.f, 0.f};
    f32x4 acc[4] = {zero, zero, zero, zero};

    for (int k0 = 0; k0 < D_MODEL; k0 += 32) {
        *reinterpret_cast<bf16x8*>(&As[srow][scg]) =
            *reinterpret_cast<const bf16x8*>(&xb[(size_t)(bm + srow) * D_MODEL + k0 + scg]);
        *reinterpret_cast<bf16x8*>(&Bs[srow][scg]) =
            *reinterpret_cast<const bf16x8*>(&wb[(size_t)(bn + srow) * D_MODEL + k0 + scg]);
        __syncthreads();
        bf16x8 a = *reinterpret_cast<const bf16x8*>(&As[w * 16 + li][lg * 8]);
#pragma unroll
        for (int cb = 0; cb < 4; ++cb) {
            bf16x8 b = *reinterpret_cast<const bf16x8*>(&Bs[cb * 16 + li][lg * 8]);
            acc[cb] = __builtin_amdgcn_mfma_f32_16x16x32_bf16(a, b, acc[cb], 0, 0, 0);
        }
        __syncthreads();
    }

    const int which = blockIdx.x >> 4;   // 0:q 1:k 2:v
    const int h = blockIdx.x & 15;
#pragma unroll
    for (int cb = 0; cb < 4; ++cb) {
        const int d = cb * 16 + li;
#pragma unroll
        for (int r = 0; r < 4; ++r) {
            const int m = bm + w * 16 + lg * 4 + r;       // = b*T + t
            const int b = m >> 11, t = m & (T_SEQ - 1);
            float v = acc[cb][r];
            if (which == 2) {
                Vt[((size_t)((b * NHEAD + h) * DK + d)) * T_SEQ + t] = f2b(v);
            } else {
                float vp = __shfl_xor(v, 1);
                int n = d >> 1;
                float c = ct[(size_t)m * 32 + n];
                float s = st[(size_t)m * 32 + n];
                float o = (d & 1) ? (v * c + vp * s) : (v * c - vp * s);
                short* dst = (which == 0) ? Qo : Ko;
                dst[((size_t)((b * NHEAD + h) * T_SEQ + t)) * DK + d] = f2b(o);
            }
        }
    }
}

// ---------------- flash attention (causal), swapped-QK^T in-register softmax ----
// 1-D grid of 1024 blocks; block -> (qtile via balanced pairing, head).
// 4 waves; wave w owns q rows [qtile*64 + 16w, +16). KVBLK = 64.
__global__ __launch_bounds__(256) void attn(const short* __restrict__ Q,
                                            const short* __restrict__ K,
                                            const short* __restrict__ Vt,
                                            short* __restrict__ Cc) {
    __shared__ short Pls[4][16][72];   // per-wave P tile, padded stride 144B
    const int bid = blockIdx.x;
    const int qt_raw = bid & 31;
    const int qtile = (qt_raw & 1) ? (31 - (qt_raw >> 1)) : (qt_raw >> 1);
    const int bh = bid >> 5;
    const int tid = threadIdx.x;
    const int w = tid >> 6, l = tid & 63, lg = l >> 4, li = l & 15;

    const short* Qh = Q + (size_t)bh * T_SEQ * DK;
    const short* Kh = K + (size_t)bh * T_SEQ * DK;
    const short* Vh = Vt + (size_t)bh * DK * T_SEQ;

    const int q0 = qtile * 64 + w * 16;
    // Q as B-operand fragments (col = q = li, k = d)
    bf16x8 qf0 = *reinterpret_cast<const bf16x8*>(&Qh[(size_t)(q0 + li) * DK + lg * 8]);
    bf16x8 qf1 = *reinterpret_cast<const bf16x8*>(&Qh[(size_t)(q0 + li) * DK + 32 + lg * 8]);

    f32x4 zero = {0.f, 0.f, 0.f, 0.f};
    f32x4 oacc[4] = {zero, zero, zero, zero};   // O[q=lg*4+r][d=cb*16+li]
    float m = -3.0e38f;   // running max, scaled(exp2) domain, for q = q0+li
    float lsum = 0.f;     // running denom for q = q0+li
    const float SCL = 0.125f * 1.44269504088896340736f;   // (1/sqrt(dk)) * log2(e)

    const int kv_end = q0 + 16;
    for (int n0 = 0; n0 < kv_end; n0 += 64) {
        // ---- QK^T swapped: s[f][r] = S^T[kv = n0+16f+lg*4+r][q = q0+li]
        f32x4 s[4];
#pragma unroll
        for (int f = 0; f < 4; ++f) {
            const short* kp = &Kh[(size_t)(n0 + 16 * f + li) * DK + lg * 8];
            bf16x8 kf0 = *reinterpret_cast<const bf16x8*>(kp);
            bf16x8 kf1 = *reinterpret_cast<const bf16x8*>(kp + 32);
            s[f] = __builtin_amdgcn_mfma_f32_16x16x32_bf16(kf0, qf0, zero, 0, 0, 0);
            s[f] = __builtin_amdgcn_mfma_f32_16x16x32_bf16(kf1, qf1, s[f], 0, 0, 0);
        }
        // ---- scale + causal mask (mask only on the diagonal step)
        float sv[16];
        const bool need_mask = (n0 + 63 > q0);
#pragma unroll
        for (int f = 0; f < 4; ++f)
#pragma unroll
            for (int r = 0; r < 4; ++r) {
                float v = s[f][r] * SCL;
                if (need_mask) {
                    int kv = n0 + 16 * f + lg * 4 + r;
                    if (kv > q0 + li) v = -3.0e38f;
                }
                sv[f * 4 + r] = v;
            }
        // ---- row max: 15 in-register + 2 shuffles
        float tm = sv[0];
#pragma unroll
        for (int i = 1; i < 16; ++i) tm = fmaxf(tm, sv[i]);
        tm = fmaxf(tm, __shfl_xor(tm, 16));
        tm = fmaxf(tm, __shfl_xor(tm, 32));
        float mnew = fmaxf(m, tm);
        // ---- P = exp2(sv - mnew) and row sum
        float ps[16];
        float rs = 0.f;
#pragma unroll
        for (int i = 0; i < 16; ++i) {
            ps[i] = __builtin_amdgcn_exp2f(sv[i] - mnew);
            rs += ps[i];
        }
        rs += __shfl_xor(rs, 16);
        rs += __shfl_xor(rs, 32);
        // ---- rescale O (skip whole pass if no lane's max grew)
        if (__any(mnew > m)) {
            float alpha = __builtin_amdgcn_exp2f(m - mnew);
            lsum = lsum * alpha + rs;
#pragma unroll
            for (int r = 0; r < 4; ++r) {
                float ar = __shfl(alpha, lg * 4 + r);
#pragma unroll
                for (int cb = 0; cb < 4; ++cb) oacc[cb][r] *= ar;
            }
        } else {
            lsum += rs;
        }
        m = mnew;
        // ---- pack P (bf16) and stage via per-wave LDS tile
#pragma unroll
        for (int f = 0; f < 4; ++f) {
            unsigned p01, p23;
            asm("v_cvt_pk_bf16_f32 %0, %1, %2" : "=v"(p01) : "v"(ps[4 * f + 0]), "v"(ps[4 * f + 1]));
            asm("v_cvt_pk_bf16_f32 %0, %1, %2" : "=v"(p23) : "v"(ps[4 * f + 2]), "v"(ps[4 * f + 3]));
            unsigned long long pp = ((unsigned long long)p23 << 32) | (unsigned long long)p01;
            *reinterpret_cast<unsigned long long*>(&Pls[w][li][16 * f + lg * 4]) = pp;
        }
        // ---- PV: A = P[q=li][kv], B = V^T fragments (contiguous from Vt)
        bf16x8 pf0 = *reinterpret_cast<const bf16x8*>(&Pls[w][li][lg * 8]);
        bf16x8 pf1 = *reinterpret_cast<const bf16x8*>(&Pls[w][li][32 + lg * 8]);
#pragma unroll
        for (int cb = 0; cb < 4; ++cb) {
            const short* vp = &Vh[(size_t)(cb * 16 + li) * T_SEQ + n0 + lg * 8];
            bf16x8 vf0 = *reinterpret_cast<const bf16x8*>(vp);
            bf16x8 vf1 = *reinterpret_cast<const bf16x8*>(vp + 32);
            oacc[cb] = __builtin_amdgcn_mfma_f32_16x16x32_bf16(pf0, vf0, oacc[cb], 0, 0, 0);
            oacc[cb] = __builtin_amdgcn_mfma_f32_16x16x32_bf16(pf1, vf1, oacc[cb], 0, 0, 0);
        }
    }

    // ---- epilogue: normalize, write concat (B, T, H*dk) bf16
    const int b = bh >> 4, h = bh & 15;
#pragma unroll
    for (int r = 0; r < 4; ++r) {
        float lr = __shfl(lsum, lg * 4 + r);
        float inv = 1.0f / lr;
        int t = q0 + lg * 4 + r;
#pragma unroll
        for (int cb = 0; cb < 4; ++cb) {
            int d = cb * 16 + li;
            Cc[((size_t)(b * T_SEQ + t)) * D_MODEL + h * DK + d] = f2b(oacc[cb][r] * inv);
        }
    }
}

// ---------------- GEMM2: out = concat * W_out^T (fp32 store) ----------------
__global__ __launch_bounds__(256) void gemm_out(const short* __restrict__ ab,
                                                const short* __restrict__ wb,
                                                float* __restrict__ out) {
    __shared__ short As[64][40];
    __shared__ short Bs[64][40];
    const int bm = blockIdx.y * 64, bn = blockIdx.x * 64;
    const int tid = threadIdx.x;
    const int w = tid >> 6, l = tid & 63, lg = l >> 4, li = l & 15;
    const int srow = tid >> 2, scg = (tid & 3) * 8;

    f32x4 zero = {0.f, 0.f, 0.f, 0.f};
    f32x4 acc[4] = {zero, zero, zero, zero};

    for (int k0 = 0; k0 < D_MODEL; k0 += 32) {
        *reinterpret_cast<bf16x8*>(&As[srow][scg]) =
            *reinterpret_cast<const bf16x8*>(&ab[(size_t)(bm + srow) * D_MODEL + k0 + scg]);
        *reinterpret_cast<bf16x8*>(&Bs[srow][scg]) =
            *reinterpret_cast<const bf16x8*>(&wb[(size_t)(bn + srow) * D_MODEL + k0 + scg]);
        __syncthreads();
        bf16x8 a = *reinterpret_cast<const bf16x8*>(&As[w * 16 + li][lg * 8]);
#pragma unroll
        for (int cb = 0; cb < 4; ++cb) {
            bf16x8 b = *reinterpret_cast<const bf16x8*>(&Bs[cb * 16 + li][lg * 8]);
            acc[cb] = __builtin_amdgcn_mfma_f32_16x16x32_bf16(a, b, acc[cb], 0, 0, 0);
        }
        __syncthreads();
    }
#pragma unroll
    for (int cb = 0; cb < 4; ++cb)
#pragma unroll
        for (int r = 0; r < 4; ++r) {
            const int m = bm + w * 16 + lg * 4 + r;
            out[(size_t)m * D_MODEL + bn + cb * 16 + li] = acc[cb][r];
        }
}

extern "C" void kernel_launch(void* const* d_in, const int* in_sizes, int n_in,
                              void* d_out, int out_size, void* d_ws, size_t ws_size,
                              hipStream_t stream) {
    const float* x    = (const float*)d_in[0];
    const int*   pos  = (const int*)d_in[1];
    const float* wqkv = (const float*)d_in[2];
    const float* wout = (const float*)d_in[3];
    float* out = (float*)d_out;

    char* ws = (char*)d_ws;
    size_t off = 0;
    short* xb  = (short*)(ws + off); off += (size_t)4096 * 1024 * 2;
    short* wqb = (short*)(ws + off); off += (size_t)3072 * 1024 * 2;
    short* wob = (short*)(ws + off); off += (size_t)1024 * 1024 * 2;
    short* Q   = (short*)(ws + off); off += (size_t)32 * 2048 * 64 * 2;
    short* Kb  = (short*)(ws + off); off += (size_t)32 * 2048 * 64 * 2;
    short* Vt  = (short*)(ws + off); off += (size_t)32 * 64 * 2048 * 2;
    off += 4096;
    short* Cc  = (short*)(ws + off); off += (size_t)4096 * 1024 * 2;
    float* ct  = (float*)(ws + off); off += (size_t)4096 * 32 * 4;
    float* st  = (float*)(ws + off); off += (size_t)4096 * 32 * 4;

    cvt_bf16<<<2048, 256, 0, stream>>>(x,    xb,  4194304 / 8);
    cvt_bf16<<<1536, 256, 0, stream>>>(wqkv, wqb, 3145728 / 8);
    cvt_bf16<<<512,  256, 0, stream>>>(wout, wob, 1048576 / 8);
    rope_table<<<512, 256, 0, stream>>>(pos, ct, st);
    gemm_qkv<<<dim3(48, 64), 256, 0, stream>>>(xb, wqb, ct, st, Q, Kb, Vt);
    attn<<<1024, 256, 0, stream>>>(Q, Kb, Vt, Cc);
    gemm_out<<<dim3(16, 64), 256, 0, stream>>>(Cc, wob, out);
}

// Round 3
// 185.036 us; speedup vs baseline: 1.8490x; 1.8490x over previous
//
#include <hip/hip_runtime.h>
#include <hip/hip_bf16.h>
#include <cmath>

#define T_SEQ 2048
#define D_MODEL 1024
#define NHEAD 16
#define DK 64

typedef short bf16x8 __attribute__((ext_vector_type(8)));
typedef float f32x4 __attribute__((ext_vector_type(4)));

// RNE float -> bf16 (finite inputs only)
__device__ __forceinline__ short f2b(float f) {
    unsigned u = __builtin_bit_cast(unsigned, f);
    unsigned r = (u + 0x7FFFu + ((u >> 16) & 1u)) >> 16;
    return (short)r;
}

// swizzled LDS access: row-stride 128B, byte col XORed with (row&7)<<4
__device__ __forceinline__ bf16x8* ldsv(short* base, int row, int colb) {
    return reinterpret_cast<bf16x8*>((char*)base + row * 128 + (colb ^ ((row & 7) << 4)));
}

// ---------------- fp32 -> bf16 convert (vectorized) ----------------
__global__ __launch_bounds__(256) void cvt_bf16(const float* __restrict__ in,
                                                short* __restrict__ out, int n8) {
    int i = blockIdx.x * blockDim.x + threadIdx.x;
    if (i >= n8) return;
    float4 a = reinterpret_cast<const float4*>(in)[2 * i];
    float4 b = reinterpret_cast<const float4*>(in)[2 * i + 1];
    bf16x8 v;
    v[0] = f2b(a.x); v[1] = f2b(a.y); v[2] = f2b(a.z); v[3] = f2b(a.w);
    v[4] = f2b(b.x); v[5] = f2b(b.y); v[6] = f2b(b.z); v[7] = f2b(b.w);
    reinterpret_cast<bf16x8*>(out)[i] = v;
}

// ---------------- RoPE cos/sin tables: (B*T, 32) ----------------
__global__ __launch_bounds__(256) void rope_table(const int* __restrict__ pos,
                                                  float* __restrict__ ct,
                                                  float* __restrict__ st) {
    int i = blockIdx.x * blockDim.x + threadIdx.x;
    int bt = i >> 5, n = i & 31;
    float p = (float)pos[bt];
    float invf = expf((float)n * (-2.0f / (float)DK) * 9.210340371976184f);
    float ang = p * invf;
    float s, c;
    sincosf(ang, &s, &c);
    ct[i] = c; st[i] = s;
}

// ---------------- GEMM1: qkv = x * W_qkv^T, fused RoPE, scatter ----------------
__global__ __launch_bounds__(256) void gemm_qkv(const short* __restrict__ xb,
                                                const short* __restrict__ wb,
                                                const float* __restrict__ ct,
                                                const float* __restrict__ st,
                                                short* __restrict__ Qo,
                                                short* __restrict__ Ko,
                                                short* __restrict__ Vt) {
    __shared__ short As[64][40];
    __shared__ short Bs[64][40];
    const int bm = blockIdx.y * 64, bn = blockIdx.x * 64;
    const int tid = threadIdx.x;
    const int w = tid >> 6, l = tid & 63, lg = l >> 4, li = l & 15;
    const int srow = tid >> 2, scg = (tid & 3) * 8;

    f32x4 zero = {0.f, 0.f, 0.f, 0.f};
    f32x4 acc[4] = {zero, zero, zero, zero};

    for (int k0 = 0; k0 < D_MODEL; k0 += 32) {
        *reinterpret_cast<bf16x8*>(&As[srow][scg]) =
            *reinterpret_cast<const bf16x8*>(&xb[(size_t)(bm + srow) * D_MODEL + k0 + scg]);
        *reinterpret_cast<bf16x8*>(&Bs[srow][scg]) =
            *reinterpret_cast<const bf16x8*>(&wb[(size_t)(bn + srow) * D_MODEL + k0 + scg]);
        __syncthreads();
        bf16x8 a = *reinterpret_cast<const bf16x8*>(&As[w * 16 + li][lg * 8]);
#pragma unroll
        for (int cb = 0; cb < 4; ++cb) {
            bf16x8 b = *reinterpret_cast<const bf16x8*>(&Bs[cb * 16 + li][lg * 8]);
            acc[cb] = __builtin_amdgcn_mfma_f32_16x16x32_bf16(a, b, acc[cb], 0, 0, 0);
        }
        __syncthreads();
    }

    const int which = blockIdx.x >> 4;   // 0:q 1:k 2:v
    const int h = blockIdx.x & 15;
#pragma unroll
    for (int cb = 0; cb < 4; ++cb) {
        const int d = cb * 16 + li;
#pragma unroll
        for (int r = 0; r < 4; ++r) {
            const int m = bm + w * 16 + lg * 4 + r;       // = b*T + t
            const int b = m >> 11, t = m & (T_SEQ - 1);
            float v = acc[cb][r];
            if (which == 2) {
                Vt[((size_t)((b * NHEAD + h) * DK + d)) * T_SEQ + t] = f2b(v);
            } else {
                float vp = __shfl_xor(v, 1);
                int n = d >> 1;
                float c = ct[(size_t)m * 32 + n];
                float s = st[(size_t)m * 32 + n];
                float o = (d & 1) ? (v * c + vp * s) : (v * c - vp * s);
                short* dst = (which == 0) ? Qo : Ko;
                dst[((size_t)((b * NHEAD + h) * T_SEQ + t)) * DK + d] = f2b(o);
            }
        }
    }
}

// ---------------- flash attention (causal) ----------------
// LDS-staged K/V tiles (reg-staged, XOR-swizzled), async prefetch of tile t+1
// during compute of tile t. Swapped QK^T, in-register softmax. KVBLK = 64.
__global__ __launch_bounds__(256, 4) void attn(const short* __restrict__ Q,
                                               const short* __restrict__ K,
                                               const short* __restrict__ Vt,
                                               short* __restrict__ Cc) {
    __shared__ short Kt[64 * 64];        // 8 KB, [kv][d] swizzled
    __shared__ short Vs[64 * 64];        // 8 KB, [d][kv] swizzled
    __shared__ short Pls[4][16 * 64];    // 8 KB, per-wave [q][kv] swizzled

    const int bid = blockIdx.x;
    const int qt_raw = bid & 31;
    const int qtile = (qt_raw & 1) ? (31 - (qt_raw >> 1)) : (qt_raw >> 1);
    const int bh = bid >> 5;
    const int tid = threadIdx.x;
    const int w = tid >> 6, l = tid & 63, lg = l >> 4, li = l & 15;
    short* Pw = &Pls[w][0];

    const short* Qh = Q + (size_t)bh * T_SEQ * DK;
    const short* Kh = K + (size_t)bh * T_SEQ * DK;
    const short* Vh = Vt + (size_t)bh * DK * T_SEQ;

    const int q0 = qtile * 64 + w * 16;
    bf16x8 qf0 = *reinterpret_cast<const bf16x8*>(&Qh[(size_t)(q0 + li) * DK + lg * 8]);
    bf16x8 qf1 = *reinterpret_cast<const bf16x8*>(&Qh[(size_t)(q0 + li) * DK + 32 + lg * 8]);

    // staging geometry: 2 chunks of 16B per thread per tile
    const int sr0 = tid >> 3;            // rows 0..31
    const int sr1 = sr0 + 32;            // rows 32..63
    const int scb = (tid & 7) * 16;      // col byte within 128B row
    const int scs = scb >> 1;            // col in shorts

    f32x4 zero = {0.f, 0.f, 0.f, 0.f};
    f32x4 oacc[4] = {zero, zero, zero, zero};
    float m = -3.0e38f;
    float lsum = 0.f;
    const float SCL = 0.125f * 1.44269504088896340736f;

    const int nt = qtile + 1;            // every wave computes every tile

    // prologue: load tile 0 into regs
    bf16x8 rk0 = *reinterpret_cast<const bf16x8*>(&Kh[(size_t)sr0 * DK + scs]);
    bf16x8 rk1 = *reinterpret_cast<const bf16x8*>(&Kh[(size_t)sr1 * DK + scs]);
    bf16x8 rv0 = *reinterpret_cast<const bf16x8*>(&Vh[(size_t)sr0 * T_SEQ + scs]);
    bf16x8 rv1 = *reinterpret_cast<const bf16x8*>(&Vh[(size_t)sr1 * T_SEQ + scs]);

    for (int t = 0; t < nt; ++t) {
        const int n0 = t * 64;
        __syncthreads();                 // previous tile's reads complete
        *ldsv(Kt, sr0, scb) = rk0;
        *ldsv(Kt, sr1, scb) = rk1;
        *ldsv(Vs, sr0, scb) = rv0;
        *ldsv(Vs, sr1, scb) = rv1;
        __syncthreads();
        if (t + 1 < nt) {                // prefetch next tile (latency hidden by compute)
            const int nn = n0 + 64;
            rk0 = *reinterpret_cast<const bf16x8*>(&Kh[(size_t)(nn + sr0) * DK + scs]);
            rk1 = *reinterpret_cast<const bf16x8*>(&Kh[(size_t)(nn + sr1) * DK + scs]);
            rv0 = *reinterpret_cast<const bf16x8*>(&Vh[(size_t)sr0 * T_SEQ + nn + scs]);
            rv1 = *reinterpret_cast<const bf16x8*>(&Vh[(size_t)sr1 * T_SEQ + nn + scs]);
        }

        // ---- QK^T swapped: s[f][r] = S^T[kv=n0+16f+lg*4+r][q=q0+li]
        f32x4 s[4];
#pragma unroll
        for (int f = 0; f < 4; ++f) {
            bf16x8 kf0 = *ldsv(Kt, 16 * f + li, lg * 16);
            bf16x8 kf1 = *ldsv(Kt, 16 * f + li, 64 + lg * 16);
            s[f] = __builtin_amdgcn_mfma_f32_16x16x32_bf16(kf0, qf0, zero, 0, 0, 0);
            s[f] = __builtin_amdgcn_mfma_f32_16x16x32_bf16(kf1, qf1, s[f], 0, 0, 0);
        }
        // ---- scale + causal mask (diagonal tile only)
        float sv[16];
        const bool need_mask = (n0 + 63 > q0);
#pragma unroll
        for (int f = 0; f < 4; ++f)
#pragma unroll
            for (int r = 0; r < 4; ++r) {
                float v = s[f][r] * SCL;
                if (need_mask) {
                    int kv = n0 + 16 * f + lg * 4 + r;
                    if (kv > q0 + li) v = -3.0e38f;
                }
                sv[f * 4 + r] = v;
            }
        // ---- row max: binary tree + 2 shuffles
        float mx = fmaxf(fmaxf(fmaxf(sv[0], sv[1]), fmaxf(sv[2], sv[3])),
                         fmaxf(fmaxf(sv[4], sv[5]), fmaxf(sv[6], sv[7])));
        float mx2 = fmaxf(fmaxf(fmaxf(sv[8], sv[9]), fmaxf(sv[10], sv[11])),
                          fmaxf(fmaxf(sv[12], sv[13]), fmaxf(sv[14], sv[15])));
        float tm = fmaxf(mx, mx2);
        tm = fmaxf(tm, __shfl_xor(tm, 16));
        tm = fmaxf(tm, __shfl_xor(tm, 32));
        float mnew = fmaxf(m, tm);
        // ---- P = exp2(sv - mnew), row sum (tree)
        float ps[16];
#pragma unroll
        for (int i = 0; i < 16; ++i) ps[i] = __builtin_amdgcn_exp2f(sv[i] - mnew);
        float rs = ((ps[0] + ps[1]) + (ps[2] + ps[3])) + ((ps[4] + ps[5]) + (ps[6] + ps[7]));
        rs += ((ps[8] + ps[9]) + (ps[10] + ps[11])) + ((ps[12] + ps[13]) + (ps[14] + ps[15]));
        rs += __shfl_xor(rs, 16);
        rs += __shfl_xor(rs, 32);
        // ---- rescale O (skip pass when no max growth)
        if (__any(mnew > m)) {
            float alpha = __builtin_amdgcn_exp2f(m - mnew);
            lsum = lsum * alpha + rs;
#pragma unroll
            for (int r = 0; r < 4; ++r) {
                float ar = __shfl(alpha, lg * 4 + r);
#pragma unroll
                for (int cb = 0; cb < 4; ++cb) oacc[cb][r] *= ar;
            }
        } else {
            lsum += rs;
        }
        m = mnew;
        // ---- pack P to bf16, bounce through per-wave swizzled LDS tile
#pragma unroll
        for (int f = 0; f < 4; ++f) {
            unsigned p01, p23;
            asm("v_cvt_pk_bf16_f32 %0, %1, %2" : "=v"(p01) : "v"(ps[4 * f + 0]), "v"(ps[4 * f + 1]));
            asm("v_cvt_pk_bf16_f32 %0, %1, %2" : "=v"(p23) : "v"(ps[4 * f + 2]), "v"(ps[4 * f + 3]));
            unsigned long long pp = ((unsigned long long)p23 << 32) | (unsigned long long)p01;
            *reinterpret_cast<unsigned long long*>(
                (char*)Pw + li * 128 + ((32 * f + lg * 8) ^ ((li & 7) << 4))) = pp;
        }
        // ---- PV: A = P[q][kv] from LDS, B = V^T[d][kv] from LDS
        bf16x8 pf0 = *ldsv(Pw, li, lg * 16);
        bf16x8 pf1 = *ldsv(Pw, li, 64 + lg * 16);
#pragma unroll
        for (int cb = 0; cb < 4; ++cb) {
            bf16x8 vf0 = *ldsv(Vs, cb * 16 + li, lg * 16);
            bf16x8 vf1 = *ldsv(Vs, cb * 16 + li, 64 + lg * 16);
            oacc[cb] = __builtin_amdgcn_mfma_f32_16x16x32_bf16(pf0, vf0, oacc[cb], 0, 0, 0);
            oacc[cb] = __builtin_amdgcn_mfma_f32_16x16x32_bf16(pf1, vf1, oacc[cb], 0, 0, 0);
        }
    }

    // ---- epilogue: normalize, write concat (B, T, H*dk) bf16
    const int b = bh >> 4, h = bh & 15;
#pragma unroll
    for (int r = 0; r < 4; ++r) {
        float lr = __shfl(lsum, lg * 4 + r);
        float inv = 1.0f / lr;
        int t = q0 + lg * 4 + r;
#pragma unroll
        for (int cb = 0; cb < 4; ++cb) {
            int d = cb * 16 + li;
            Cc[((size_t)(b * T_SEQ + t)) * D_MODEL + h * DK + d] = f2b(oacc[cb][r] * inv);
        }
    }
}

// ---------------- GEMM2: out = concat * W_out^T (fp32 store) ----------------
__global__ __launch_bounds__(256) void gemm_out(const short* __restrict__ ab,
                                                const short* __restrict__ wb,
                                                float* __restrict__ out) {
    __shared__ short As[64][40];
    __shared__ short Bs[64][40];
    const int bm = blockIdx.y * 64, bn = blockIdx.x * 64;
    const int tid = threadIdx.x;
    const int w = tid >> 6, l = tid & 63, lg = l >> 4, li = l & 15;
    const int srow = tid >> 2, scg = (tid & 3) * 8;

    f32x4 zero = {0.f, 0.f, 0.f, 0.f};
    f32x4 acc[4] = {zero, zero, zero, zero};

    for (int k0 = 0; k0 < D_MODEL; k0 += 32) {
        *reinterpret_cast<bf16x8*>(&As[srow][scg]) =
            *reinterpret_cast<const bf16x8*>(&ab[(size_t)(bm + srow) * D_MODEL + k0 + scg]);
        *reinterpret_cast<bf16x8*>(&Bs[srow][scg]) =
            *reinterpret_cast<const bf16x8*>(&wb[(size_t)(bn + srow) * D_MODEL + k0 + scg]);
        __syncthreads();
        bf16x8 a = *reinterpret_cast<const bf16x8*>(&As[w * 16 + li][lg * 8]);
#pragma unroll
        for (int cb = 0; cb < 4; ++cb) {
            bf16x8 b = *reinterpret_cast<const bf16x8*>(&Bs[cb * 16 + li][lg * 8]);
            acc[cb] = __builtin_amdgcn_mfma_f32_16x16x32_bf16(a, b, acc[cb], 0, 0, 0);
        }
        __syncthreads();
    }
#pragma unroll
    for (int cb = 0; cb < 4; ++cb)
#pragma unroll
        for (int r = 0; r < 4; ++r) {
            const int m = bm + w * 16 + lg * 4 + r;
            out[(size_t)m * D_MODEL + bn + cb * 16 + li] = acc[cb][r];
        }
}

extern "C" void kernel_launch(void* const* d_in, const int* in_sizes, int n_in,
                              void* d_out, int out_size, void* d_ws, size_t ws_size,
                              hipStream_t stream) {
    const float* x    = (const float*)d_in[0];
    const int*   pos  = (const int*)d_in[1];
    const float* wqkv = (const float*)d_in[2];
    const float* wout = (const float*)d_in[3];
    float* out = (float*)d_out;

    char* ws = (char*)d_ws;
    size_t off = 0;
    short* xb  = (short*)(ws + off); off += (size_t)4096 * 1024 * 2;
    short* wqb = (short*)(ws + off); off += (size_t)3072 * 1024 * 2;
    short* wob = (short*)(ws + off); off += (size_t)1024 * 1024 * 2;
    short* Q   = (short*)(ws + off); off += (size_t)32 * 2048 * 64 * 2;
    short* Kb  = (short*)(ws + off); off += (size_t)32 * 2048 * 64 * 2;
    short* Vt  = (short*)(ws + off); off += (size_t)32 * 64 * 2048 * 2;
    off += 4096;
    short* Cc  = (short*)(ws + off); off += (size_t)4096 * 1024 * 2;
    float* ct  = (float*)(ws + off); off += (size_t)4096 * 32 * 4;
    float* st  = (float*)(ws + off); off += (size_t)4096 * 32 * 4;

    cvt_bf16<<<2048, 256, 0, stream>>>(x,    xb,  4194304 / 8);
    cvt_bf16<<<1536, 256, 0, stream>>>(wqkv, wqb, 3145728 / 8);
    cvt_bf16<<<512,  256, 0, stream>>>(wout, wob, 1048576 / 8);
    rope_table<<<512, 256, 0, stream>>>(pos, ct, st);
    gemm_qkv<<<dim3(48, 64), 256, 0, stream>>>(xb, wqb, ct, st, Q, Kb, Vt);
    attn<<<1024, 256, 0, stream>>>(Q, Kb, Vt, Cc);
    gemm_out<<<dim3(16, 64), 256, 0, stream>>>(Cc, wob, out);
}

// Round 4
// 177.081 us; speedup vs baseline: 1.9320x; 1.0449x over previous
//
#include <hip/hip_runtime.h>
#include <hip/hip_bf16.h>
#include <cmath>

#define T_SEQ 2048
#define D_MODEL 1024
#define NHEAD 16
#define DK 64

typedef short bf16x8 __attribute__((ext_vector_type(8)));
typedef float f32x4 __attribute__((ext_vector_type(4)));

// RNE float -> bf16 (finite inputs only)
__device__ __forceinline__ short f2b(float f) {
    unsigned u = __builtin_bit_cast(unsigned, f);
    unsigned r = (u + 0x7FFFu + ((u >> 16) & 1u)) >> 16;
    return (short)r;
}

// async global->LDS, 16B per lane; lds base must be wave-uniform (HW adds lane*16)
__device__ __forceinline__ void gll16(const void* g, void* l) {
    __builtin_amdgcn_global_load_lds(
        (__attribute__((address_space(1))) void*)g,
        (__attribute__((address_space(3))) void*)l, 16, 0, 0);
}

// swizzled LDS access for attn tiles: row-stride 128B, byte col XORed with (row&7)<<4
__device__ __forceinline__ bf16x8* ldsv(short* base, int row, int colb) {
    return reinterpret_cast<bf16x8*>((char*)base + row * 128 + (colb ^ ((row & 7) << 4)));
}

// ---------------- fused fp32 -> bf16 convert for x, W_qkv, W_out ----------------
__global__ __launch_bounds__(256) void cvt_all(const float* __restrict__ x,
                                               const float* __restrict__ wq,
                                               const float* __restrict__ wo,
                                               short* __restrict__ xb,
                                               short* __restrict__ wqb,
                                               short* __restrict__ wob) {
    int i = blockIdx.x * 256 + threadIdx.x;   // 1048576 8-elem units total
    const float* src; short* dst; int j = i;
    if (j < 524288)      { src = x;  dst = xb; }
    else if (j < 917504) { src = wq; dst = wqb; j -= 524288; }
    else                 { src = wo; dst = wob; j -= 917504; }
    float4 a = reinterpret_cast<const float4*>(src)[2 * j];
    float4 b = reinterpret_cast<const float4*>(src)[2 * j + 1];
    bf16x8 v;
    v[0] = f2b(a.x); v[1] = f2b(a.y); v[2] = f2b(a.z); v[3] = f2b(a.w);
    v[4] = f2b(b.x); v[5] = f2b(b.y); v[6] = f2b(b.z); v[7] = f2b(b.w);
    reinterpret_cast<bf16x8*>(dst)[j] = v;
}

// ---------------- RoPE cos/sin tables: (B*T, 32) ----------------
__global__ __launch_bounds__(256) void rope_table(const int* __restrict__ pos,
                                                  float* __restrict__ ct,
                                                  float* __restrict__ st) {
    int i = blockIdx.x * blockDim.x + threadIdx.x;
    int bt = i >> 5, n = i & 31;
    float p = (float)pos[bt];
    float invf = expf((float)n * (-2.0f / (float)DK) * 9.210340371976184f);
    float ang = p * invf;
    float s, c;
    sincosf(ang, &s, &c);
    ct[i] = c; st[i] = s;
}

// ---------------- GEMM1: qkv = x * W_qkv^T, fused RoPE, scatter ----------------
// 128x128 tile, 4 waves (2x2), BK=32, k-slab LDS layout [kblk][128 rows][8 shorts],
// double-buffered, global_load_lds width 16, 2-phase pipeline.
__global__ __launch_bounds__(256, 3) void gemm_qkv(const short* __restrict__ xb,
                                                   const short* __restrict__ wb,
                                                   const float* __restrict__ ct,
                                                   const float* __restrict__ st,
                                                   short* __restrict__ Qo,
                                                   short* __restrict__ Ko,
                                                   short* __restrict__ Vt) {
    __shared__ short As[2][4096];
    __shared__ short Bs[2][4096];
    const int bn = blockIdx.x * 128, bm = blockIdx.y * 128;
    const int tid = threadIdx.x;
    const int w = tid >> 6, l = tid & 63, lg = l >> 4, li = l & 15;
    const int wr = w >> 1, wc = w & 1;

    // staging: wave w owns k-slab w; rows l and 64+l (chunk = w*128 + row)
    const short* gA0 = xb + (size_t)(bm + l) * D_MODEL + w * 8;
    const short* gA1 = gA0 + (size_t)64 * D_MODEL;
    const short* gB0 = wb + (size_t)(bn + l) * D_MODEL + w * 8;
    const short* gB1 = gB0 + (size_t)64 * D_MODEL;

    f32x4 zero = {0.f, 0.f, 0.f, 0.f};
    f32x4 acc[4][4];
#pragma unroll
    for (int m = 0; m < 4; ++m)
#pragma unroll
        for (int n = 0; n < 4; ++n) acc[m][n] = zero;

    // prologue: stage tile 0 into buf 0
    gll16(gA0, &As[0][w * 1024]);
    gll16(gA1, &As[0][w * 1024 + 512]);
    gll16(gB0, &Bs[0][w * 1024]);
    gll16(gB1, &Bs[0][w * 1024 + 512]);
    __syncthreads();

    for (int t = 0; t < 32; ++t) {
        if (t < 31) {   // stage tile t+1 into the other buffer (in flight during compute)
            const int nb = (t + 1) & 1;
            const int ko = (t + 1) * 32;
            gll16(gA0 + ko, &As[nb][w * 1024]);
            gll16(gA1 + ko, &As[nb][w * 1024 + 512]);
            gll16(gB0 + ko, &Bs[nb][w * 1024]);
            gll16(gB1 + ko, &Bs[nb][w * 1024 + 512]);
        }
        const int cb = t & 1;
        bf16x8 a[4], b[4];
#pragma unroll
        for (int m = 0; m < 4; ++m)
            a[m] = *reinterpret_cast<const bf16x8*>(&As[cb][lg * 1024 + (wr * 64 + m * 16 + li) * 8]);
#pragma unroll
        for (int n = 0; n < 4; ++n)
            b[n] = *reinterpret_cast<const bf16x8*>(&Bs[cb][lg * 1024 + (wc * 64 + n * 16 + li) * 8]);
#pragma unroll
        for (int m = 0; m < 4; ++m)
#pragma unroll
            for (int n = 0; n < 4; ++n)
                acc[m][n] = __builtin_amdgcn_mfma_f32_16x16x32_bf16(a[m], b[n], acc[m][n], 0, 0, 0);
        __syncthreads();   // drains staged loads (vmcnt) + this tile's reads (lgkm)
    }

    // epilogue: block-uniform which; head = f(bn, wc); RoPE for Q/K; V transposed
    const int which = bn >> 10;                 // 0:q 1:k 2:v
    const int h = ((bn >> 6) + wc) & 15;
#pragma unroll
    for (int n = 0; n < 4; ++n) {
        const int d = n * 16 + li;              // col within head
#pragma unroll
        for (int m = 0; m < 4; ++m)
#pragma unroll
            for (int r = 0; r < 4; ++r) {
                const int mi = bm + wr * 64 + m * 16 + lg * 4 + r;   // = b*T + t
                const int b_ = mi >> 11, tt = mi & (T_SEQ - 1);
                float v = acc[m][n][r];
                if (which == 2) {
                    Vt[((size_t)((b_ * NHEAD + h) * DK + d)) * T_SEQ + tt] = f2b(v);
                } else {
                    float vp = __shfl_xor(v, 1);
                    int nn = n * 8 + (li >> 1);
                    float c = ct[(size_t)mi * 32 + nn];
                    float s = st[(size_t)mi * 32 + nn];
                    float o = (d & 1) ? (v * c + vp * s) : (v * c - vp * s);
                    short* dst = (which == 0) ? Qo : Ko;
                    dst[((size_t)((b_ * NHEAD + h) * T_SEQ + tt)) * DK + d] = f2b(o);
                }
            }
    }
}

// ---------------- flash attention (causal) — unchanged from round 3 ----------------
__global__ __launch_bounds__(256, 4) void attn(const short* __restrict__ Q,
                                               const short* __restrict__ K,
                                               const short* __restrict__ Vt,
                                               short* __restrict__ Cc) {
    __shared__ short Kt[64 * 64];
    __shared__ short Vs[64 * 64];
    __shared__ short Pls[4][16 * 64];

    const int bid = blockIdx.x;
    const int qt_raw = bid & 31;
    const int qtile = (qt_raw & 1) ? (31 - (qt_raw >> 1)) : (qt_raw >> 1);
    const int bh = bid >> 5;
    const int tid = threadIdx.x;
    const int w = tid >> 6, l = tid & 63, lg = l >> 4, li = l & 15;
    short* Pw = &Pls[w][0];

    const short* Qh = Q + (size_t)bh * T_SEQ * DK;
    const short* Kh = K + (size_t)bh * T_SEQ * DK;
    const short* Vh = Vt + (size_t)bh * DK * T_SEQ;

    const int q0 = qtile * 64 + w * 16;
    bf16x8 qf0 = *reinterpret_cast<const bf16x8*>(&Qh[(size_t)(q0 + li) * DK + lg * 8]);
    bf16x8 qf1 = *reinterpret_cast<const bf16x8*>(&Qh[(size_t)(q0 + li) * DK + 32 + lg * 8]);

    const int sr0 = tid >> 3;
    const int sr1 = sr0 + 32;
    const int scb = (tid & 7) * 16;
    const int scs = scb >> 1;

    f32x4 zero = {0.f, 0.f, 0.f, 0.f};
    f32x4 oacc[4] = {zero, zero, zero, zero};
    float m = -3.0e38f;
    float lsum = 0.f;
    const float SCL = 0.125f * 1.44269504088896340736f;

    const int nt = qtile + 1;

    bf16x8 rk0 = *reinterpret_cast<const bf16x8*>(&Kh[(size_t)sr0 * DK + scs]);
    bf16x8 rk1 = *reinterpret_cast<const bf16x8*>(&Kh[(size_t)sr1 * DK + scs]);
    bf16x8 rv0 = *reinterpret_cast<const bf16x8*>(&Vh[(size_t)sr0 * T_SEQ + scs]);
    bf16x8 rv1 = *reinterpret_cast<const bf16x8*>(&Vh[(size_t)sr1 * T_SEQ + scs]);

    for (int t = 0; t < nt; ++t) {
        const int n0 = t * 64;
        __syncthreads();
        *ldsv(Kt, sr0, scb) = rk0;
        *ldsv(Kt, sr1, scb) = rk1;
        *ldsv(Vs, sr0, scb) = rv0;
        *ldsv(Vs, sr1, scb) = rv1;
        __syncthreads();
        if (t + 1 < nt) {
            const int nn = n0 + 64;
            rk0 = *reinterpret_cast<const bf16x8*>(&Kh[(size_t)(nn + sr0) * DK + scs]);
            rk1 = *reinterpret_cast<const bf16x8*>(&Kh[(size_t)(nn + sr1) * DK + scs]);
            rv0 = *reinterpret_cast<const bf16x8*>(&Vh[(size_t)sr0 * T_SEQ + nn + scs]);
            rv1 = *reinterpret_cast<const bf16x8*>(&Vh[(size_t)sr1 * T_SEQ + nn + scs]);
        }

        f32x4 s[4];
#pragma unroll
        for (int f = 0; f < 4; ++f) {
            bf16x8 kf0 = *ldsv(Kt, 16 * f + li, lg * 16);
            bf16x8 kf1 = *ldsv(Kt, 16 * f + li, 64 + lg * 16);
            s[f] = __builtin_amdgcn_mfma_f32_16x16x32_bf16(kf0, qf0, zero, 0, 0, 0);
            s[f] = __builtin_amdgcn_mfma_f32_16x16x32_bf16(kf1, qf1, s[f], 0, 0, 0);
        }
        float sv[16];
        const bool need_mask = (n0 + 63 > q0);
#pragma unroll
        for (int f = 0; f < 4; ++f)
#pragma unroll
            for (int r = 0; r < 4; ++r) {
                float v = s[f][r] * SCL;
                if (need_mask) {
                    int kv = n0 + 16 * f + lg * 4 + r;
                    if (kv > q0 + li) v = -3.0e38f;
                }
                sv[f * 4 + r] = v;
            }
        float mx = fmaxf(fmaxf(fmaxf(sv[0], sv[1]), fmaxf(sv[2], sv[3])),
                         fmaxf(fmaxf(sv[4], sv[5]), fmaxf(sv[6], sv[7])));
        float mx2 = fmaxf(fmaxf(fmaxf(sv[8], sv[9]), fmaxf(sv[10], sv[11])),
                          fmaxf(fmaxf(sv[12], sv[13]), fmaxf(sv[14], sv[15])));
        float tm = fmaxf(mx, mx2);
        tm = fmaxf(tm, __shfl_xor(tm, 16));
        tm = fmaxf(tm, __shfl_xor(tm, 32));
        float mnew = fmaxf(m, tm);
        float ps[16];
#pragma unroll
        for (int i = 0; i < 16; ++i) ps[i] = __builtin_amdgcn_exp2f(sv[i] - mnew);
        float rs = ((ps[0] + ps[1]) + (ps[2] + ps[3])) + ((ps[4] + ps[5]) + (ps[6] + ps[7]));
        rs += ((ps[8] + ps[9]) + (ps[10] + ps[11])) + ((ps[12] + ps[13]) + (ps[14] + ps[15]));
        rs += __shfl_xor(rs, 16);
        rs += __shfl_xor(rs, 32);
        if (__any(mnew > m)) {
            float alpha = __builtin_amdgcn_exp2f(m - mnew);
            lsum = lsum * alpha + rs;
#pragma unroll
            for (int r = 0; r < 4; ++r) {
                float ar = __shfl(alpha, lg * 4 + r);
#pragma unroll
                for (int cbq = 0; cbq < 4; ++cbq) oacc[cbq][r] *= ar;
            }
        } else {
            lsum += rs;
        }
        m = mnew;
#pragma unroll
        for (int f = 0; f < 4; ++f) {
            unsigned p01, p23;
            asm("v_cvt_pk_bf16_f32 %0, %1, %2" : "=v"(p01) : "v"(ps[4 * f + 0]), "v"(ps[4 * f + 1]));
            asm("v_cvt_pk_bf16_f32 %0, %1, %2" : "=v"(p23) : "v"(ps[4 * f + 2]), "v"(ps[4 * f + 3]));
            unsigned long long pp = ((unsigned long long)p23 << 32) | (unsigned long long)p01;
            *reinterpret_cast<unsigned long long*>(
                (char*)Pw + li * 128 + ((32 * f + lg * 8) ^ ((li & 7) << 4))) = pp;
        }
        bf16x8 pf0 = *ldsv(Pw, li, lg * 16);
        bf16x8 pf1 = *ldsv(Pw, li, 64 + lg * 16);
#pragma unroll
        for (int cbq = 0; cbq < 4; ++cbq) {
            bf16x8 vf0 = *ldsv(Vs, cbq * 16 + li, lg * 16);
            bf16x8 vf1 = *ldsv(Vs, cbq * 16 + li, 64 + lg * 16);
            oacc[cbq] = __builtin_amdgcn_mfma_f32_16x16x32_bf16(pf0, vf0, oacc[cbq], 0, 0, 0);
            oacc[cbq] = __builtin_amdgcn_mfma_f32_16x16x32_bf16(pf1, vf1, oacc[cbq], 0, 0, 0);
        }
    }

    const int b = bh >> 4, h = bh & 15;
#pragma unroll
    for (int r = 0; r < 4; ++r) {
        float lr = __shfl(lsum, lg * 4 + r);
        float inv = 1.0f / lr;
        int t = q0 + lg * 4 + r;
#pragma unroll
        for (int cbq = 0; cbq < 4; ++cbq) {
            int d = cbq * 16 + li;
            Cc[((size_t)(b * T_SEQ + t)) * D_MODEL + h * DK + d] = f2b(oacc[cbq][r] * inv);
        }
    }
}

// ---------------- GEMM2: out = concat * W_out^T (fp32 store) ----------------
// 128x64 tile, 4 waves (2x2), wave tile 64x32, same pipeline as gemm_qkv.
__global__ __launch_bounds__(256, 3) void gemm_out(const short* __restrict__ ab,
                                                   const short* __restrict__ wb,
                                                   float* __restrict__ out) {
    __shared__ short As[2][4096];
    __shared__ short Bs[2][2048];
    const int bn = blockIdx.x * 64, bm = blockIdx.y * 128;
    const int tid = threadIdx.x;
    const int w = tid >> 6, l = tid & 63, lg = l >> 4, li = l & 15;
    const int wr = w >> 1, wc = w & 1;

    const short* gA0 = ab + (size_t)(bm + l) * D_MODEL + w * 8;
    const short* gA1 = gA0 + (size_t)64 * D_MODEL;
    const short* gB0 = wb + (size_t)(bn + l) * D_MODEL + w * 8;

    f32x4 zero = {0.f, 0.f, 0.f, 0.f};
    f32x4 acc[4][2];
#pragma unroll
    for (int m = 0; m < 4; ++m)
#pragma unroll
        for (int n = 0; n < 2; ++n) acc[m][n] = zero;

    gll16(gA0, &As[0][w * 1024]);
    gll16(gA1, &As[0][w * 1024 + 512]);
    gll16(gB0, &Bs[0][w * 512]);
    __syncthreads();

    for (int t = 0; t < 32; ++t) {
        if (t < 31) {
            const int nb = (t + 1) & 1;
            const int ko = (t + 1) * 32;
            gll16(gA0 + ko, &As[nb][w * 1024]);
            gll16(gA1 + ko, &As[nb][w * 1024 + 512]);
            gll16(gB0 + ko, &Bs[nb][w * 512]);
        }
        const int cb = t & 1;
        bf16x8 a[4], b[2];
#pragma unroll
        for (int m = 0; m < 4; ++m)
            a[m] = *reinterpret_cast<const bf16x8*>(&As[cb][lg * 1024 + (wr * 64 + m * 16 + li) * 8]);
#pragma unroll
        for (int n = 0; n < 2; ++n)
            b[n] = *reinterpret_cast<const bf16x8*>(&Bs[cb][lg * 512 + (wc * 32 + n * 16 + li) * 8]);
#pragma unroll
        for (int m = 0; m < 4; ++m)
#pragma unroll
            for (int n = 0; n < 2; ++n)
                acc[m][n] = __builtin_amdgcn_mfma_f32_16x16x32_bf16(a[m], b[n], acc[m][n], 0, 0, 0);
        __syncthreads();
    }

#pragma unroll
    for (int m = 0; m < 4; ++m)
#pragma unroll
        for (int n = 0; n < 2; ++n)
#pragma unroll
            for (int r = 0; r < 4; ++r) {
                const int mi = bm + wr * 64 + m * 16 + lg * 4 + r;
                out[(size_t)mi * D_MODEL + bn + wc * 32 + n * 16 + li] = acc[m][n][r];
            }
}

extern "C" void kernel_launch(void* const* d_in, const int* in_sizes, int n_in,
                              void* d_out, int out_size, void* d_ws, size_t ws_size,
                              hipStream_t stream) {
    const float* x    = (const float*)d_in[0];
    const int*   pos  = (const int*)d_in[1];
    const float* wqkv = (const float*)d_in[2];
    const float* wout = (const float*)d_in[3];
    float* out = (float*)d_out;

    char* ws = (char*)d_ws;
    size_t off = 0;
    short* xb  = (short*)(ws + off); off += (size_t)4096 * 1024 * 2;
    short* wqb = (short*)(ws + off); off += (size_t)3072 * 1024 * 2;
    short* wob = (short*)(ws + off); off += (size_t)1024 * 1024 * 2;
    short* Q   = (short*)(ws + off); off += (size_t)32 * 2048 * 64 * 2;
    short* Kb  = (short*)(ws + off); off += (size_t)32 * 2048 * 64 * 2;
    short* Vt  = (short*)(ws + off); off += (size_t)32 * 64 * 2048 * 2;
    off += 4096;
    short* Cc  = (short*)(ws + off); off += (size_t)4096 * 1024 * 2;
    float* ct  = (float*)(ws + off); off += (size_t)4096 * 32 * 4;
    float* st  = (float*)(ws + off); off += (size_t)4096 * 32 * 4;

    cvt_all<<<4096, 256, 0, stream>>>(x, wqkv, wout, xb, wqb, wob);
    rope_table<<<512, 256, 0, stream>>>(pos, ct, st);
    gemm_qkv<<<dim3(24, 32), 256, 0, stream>>>(xb, wqb, ct, st, Q, Kb, Vt);
    attn<<<1024, 256, 0, stream>>>(Q, Kb, Vt, Cc);
    gemm_out<<<dim3(16, 32), 256, 0, stream>>>(Cc, wob, out);
}

// Round 5
// 152.736 us; speedup vs baseline: 2.2400x; 1.1594x over previous
//
#include <hip/hip_runtime.h>
#include <hip/hip_bf16.h>
#include <cmath>

#define T_SEQ 2048
#define D_MODEL 1024
#define NHEAD 16
#define DK 64

typedef short bf16x8 __attribute__((ext_vector_type(8)));
typedef float f32x4 __attribute__((ext_vector_type(4)));

// RNE float -> bf16 (finite inputs only)
__device__ __forceinline__ short f2b(float f) {
    unsigned u = __builtin_bit_cast(unsigned, f);
    unsigned r = (u + 0x7FFFu + ((u >> 16) & 1u)) >> 16;
    return (short)r;
}

// async global->LDS, 16B per lane; lds base wave-uniform (HW adds lane*16)
__device__ __forceinline__ void gll16(const void* g, void* l) {
    __builtin_amdgcn_global_load_lds(
        (__attribute__((address_space(1))) void*)g,
        (__attribute__((address_space(3))) void*)l, 16, 0, 0);
}

// swizzled LDS access for attn tiles: row-stride 128B, byte col XORed with (row&7)<<4
__device__ __forceinline__ bf16x8* ldsv(short* base, int row, int colb) {
    return reinterpret_cast<bf16x8*>((char*)base + row * 128 + (colb ^ ((row & 7) << 4)));
}

// ================= fused fp32 -> bf16 convert into TILED layouts =================
// xb_t / wqb_t: 128-row tiles: offset = (rb*32+kb)*4096 + kblk*1024 + row*8 + e
//   (rb = row-block of 128, kb = k-block of 32, kblk = 8-wide sub-block)
// wob_t: 64-row tiles:        offset = (nb*32+kb)*2048 + kblk*512 + row*8 + e
// One thread per 16B output chunk => gll16 staging later is lane-contiguous.
__global__ __launch_bounds__(256) void cvt_all(const float* __restrict__ x,
                                               const float* __restrict__ wq,
                                               const float* __restrict__ wo,
                                               short* __restrict__ xb,
                                               short* __restrict__ wqb,
                                               short* __restrict__ wob) {
    int i = blockIdx.x * 256 + threadIdx.x;   // 1048576 chunks total
    const float* src;
    short* dst;
    int srcoff, c;
    if (i < 524288) {                 // xb: 32 rb x 32 kb tiles
        c = i;
        int tile = c >> 9, cc = c & 511;
        int kblk = cc >> 7, row = cc & 127;
        int rb = tile >> 5, kb = tile & 31;
        srcoff = (rb * 128 + row) * D_MODEL + kb * 32 + kblk * 8;
        src = x; dst = xb;
    } else if (i < 917504) {          // wqb: 24 nb x 32 kb tiles
        c = i - 524288;
        int tile = c >> 9, cc = c & 511;
        int kblk = cc >> 7, row = cc & 127;
        int rb = tile >> 5, kb = tile & 31;
        srcoff = (rb * 128 + row) * D_MODEL + kb * 32 + kblk * 8;
        src = wq; dst = wqb;
    } else {                          // wob: 16 nb x 32 kb tiles (64-row)
        c = i - 917504;
        int tile = c >> 8, cc = c & 255;
        int kblk = cc >> 6, row = cc & 63;
        int nb = tile >> 5, kb = tile & 31;
        srcoff = (nb * 64 + row) * D_MODEL + kb * 32 + kblk * 8;
        src = wo; dst = wob;
    }
    float4 a = *reinterpret_cast<const float4*>(src + srcoff);
    float4 b = *reinterpret_cast<const float4*>(src + srcoff + 4);
    bf16x8 v;
    v[0] = f2b(a.x); v[1] = f2b(a.y); v[2] = f2b(a.z); v[3] = f2b(a.w);
    v[4] = f2b(b.x); v[5] = f2b(b.y); v[6] = f2b(b.z); v[7] = f2b(b.w);
    reinterpret_cast<bf16x8*>(dst)[c] = v;
}

// ---------------- RoPE cos/sin tables: (B*T, 32) ----------------
__global__ __launch_bounds__(256) void rope_table(const int* __restrict__ pos,
                                                  float* __restrict__ ct,
                                                  float* __restrict__ st) {
    int i = blockIdx.x * blockDim.x + threadIdx.x;
    int bt = i >> 5, n = i & 31;
    float p = (float)pos[bt];
    float invf = expf((float)n * (-2.0f / (float)DK) * 9.210340371976184f);
    float ang = p * invf;
    float s, c;
    sincosf(ang, &s, &c);
    ct[i] = c; st[i] = s;
}

// ---------------- GEMM1: qkv = x * W_qkv^T, fused RoPE, scatter ----------------
// 128x128 tile, 4 waves (2x2), BK=32. Tiled inputs => gll16 sources contiguous 1KB.
// LDS k-slab [kblk][row][8]: fragment reads are 16-lane-contiguous (conflict-free).
__global__ __launch_bounds__(256, 3) void gemm_qkv(const short* __restrict__ xb,
                                                   const short* __restrict__ wb,
                                                   const float* __restrict__ ct,
                                                   const float* __restrict__ st,
                                                   short* __restrict__ Qo,
                                                   short* __restrict__ Ko,
                                                   short* __restrict__ Vt) {
    __shared__ short As[2][4096];
    __shared__ short Bs[2][4096];
    const int tid = threadIdx.x;
    const int w = tid >> 6, l = tid & 63, lg = l >> 4, li = l & 15;
    const int wr = w >> 1, wc = w & 1;
    const int bn = blockIdx.x * 128, bm = blockIdx.y * 128;

    // per-lane contiguous staging pointers (chunk = w*128 + j*64 + lane)
    const short* pA = xb + (size_t)blockIdx.y * 32 * 4096 + (w * 128 + l) * 8;
    const short* pB = wb + (size_t)blockIdx.x * 32 * 4096 + (w * 128 + l) * 8;

    f32x4 zero = {0.f, 0.f, 0.f, 0.f};
    f32x4 acc[4][4];
#pragma unroll
    for (int m = 0; m < 4; ++m)
#pragma unroll
        for (int n = 0; n < 4; ++n) acc[m][n] = zero;

    gll16(pA,       &As[0][w * 1024]);
    gll16(pA + 512, &As[0][w * 1024 + 512]);
    gll16(pB,       &Bs[0][w * 1024]);
    gll16(pB + 512, &Bs[0][w * 1024 + 512]);
    __syncthreads();

    for (int t = 0; t < 32; ++t) {
        if (t < 31) {
            const int nb = (t + 1) & 1;
            const size_t ko = (size_t)(t + 1) * 4096;
            gll16(pA + ko,       &As[nb][w * 1024]);
            gll16(pA + ko + 512, &As[nb][w * 1024 + 512]);
            gll16(pB + ko,       &Bs[nb][w * 1024]);
            gll16(pB + ko + 512, &Bs[nb][w * 1024 + 512]);
        }
        const int cb = t & 1;
        bf16x8 a[4], b[4];
#pragma unroll
        for (int m = 0; m < 4; ++m)
            a[m] = *reinterpret_cast<const bf16x8*>(&As[cb][lg * 1024 + (wr * 64 + m * 16 + li) * 8]);
#pragma unroll
        for (int n = 0; n < 4; ++n)
            b[n] = *reinterpret_cast<const bf16x8*>(&Bs[cb][lg * 1024 + (wc * 64 + n * 16 + li) * 8]);
#pragma unroll
        for (int m = 0; m < 4; ++m)
#pragma unroll
            for (int n = 0; n < 4; ++n)
                acc[m][n] = __builtin_amdgcn_mfma_f32_16x16x32_bf16(a[m], b[n], acc[m][n], 0, 0, 0);
        __syncthreads();
    }

    // epilogue: which is block-uniform; head = f(bn, wc); RoPE for Q/K; V transposed
    const int which = bn >> 10;                 // 0:q 1:k 2:v
    const int h = ((bn >> 6) + wc) & 15;
#pragma unroll
    for (int n = 0; n < 4; ++n) {
        const int d = n * 16 + li;
#pragma unroll
        for (int m = 0; m < 4; ++m)
#pragma unroll
            for (int r = 0; r < 4; ++r) {
                const int mi = bm + wr * 64 + m * 16 + lg * 4 + r;   // = b*T + t
                const int b_ = mi >> 11, tt = mi & (T_SEQ - 1);
                float v = acc[m][n][r];
                if (which == 2) {
                    Vt[((size_t)((b_ * NHEAD + h) * DK + d)) * T_SEQ + tt] = f2b(v);
                } else {
                    float vp = __shfl_xor(v, 1);
                    int nn = n * 8 + (li >> 1);
                    float c = ct[(size_t)mi * 32 + nn];
                    float s = st[(size_t)mi * 32 + nn];
                    float o = (d & 1) ? (v * c + vp * s) : (v * c - vp * s);
                    short* dst = (which == 0) ? Qo : Ko;
                    dst[((size_t)((b_ * NHEAD + h) * T_SEQ + tt)) * DK + d] = f2b(o);
                }
            }
    }
}

// ---------------- flash attention (causal) — epilogue now writes tiled Cc ----------
__global__ __launch_bounds__(256, 4) void attn(const short* __restrict__ Q,
                                               const short* __restrict__ K,
                                               const short* __restrict__ Vt,
                                               short* __restrict__ Cc) {
    __shared__ short Kt[64 * 64];
    __shared__ short Vs[64 * 64];
    __shared__ short Pls[4][16 * 64];

    const int bid = blockIdx.x;
    const int qt_raw = bid & 31;
    const int qtile = (qt_raw & 1) ? (31 - (qt_raw >> 1)) : (qt_raw >> 1);
    const int bh = bid >> 5;
    const int tid = threadIdx.x;
    const int w = tid >> 6, l = tid & 63, lg = l >> 4, li = l & 15;
    short* Pw = &Pls[w][0];

    const short* Qh = Q + (size_t)bh * T_SEQ * DK;
    const short* Kh = K + (size_t)bh * T_SEQ * DK;
    const short* Vh = Vt + (size_t)bh * DK * T_SEQ;

    const int q0 = qtile * 64 + w * 16;
    bf16x8 qf0 = *reinterpret_cast<const bf16x8*>(&Qh[(size_t)(q0 + li) * DK + lg * 8]);
    bf16x8 qf1 = *reinterpret_cast<const bf16x8*>(&Qh[(size_t)(q0 + li) * DK + 32 + lg * 8]);

    const int sr0 = tid >> 3;
    const int sr1 = sr0 + 32;
    const int scb = (tid & 7) * 16;
    const int scs = scb >> 1;

    f32x4 zero = {0.f, 0.f, 0.f, 0.f};
    f32x4 oacc[4] = {zero, zero, zero, zero};
    float m = -3.0e38f;
    float lsum = 0.f;
    const float SCL = 0.125f * 1.44269504088896340736f;

    const int nt = qtile + 1;

    bf16x8 rk0 = *reinterpret_cast<const bf16x8*>(&Kh[(size_t)sr0 * DK + scs]);
    bf16x8 rk1 = *reinterpret_cast<const bf16x8*>(&Kh[(size_t)sr1 * DK + scs]);
    bf16x8 rv0 = *reinterpret_cast<const bf16x8*>(&Vh[(size_t)sr0 * T_SEQ + scs]);
    bf16x8 rv1 = *reinterpret_cast<const bf16x8*>(&Vh[(size_t)sr1 * T_SEQ + scs]);

    for (int t = 0; t < nt; ++t) {
        const int n0 = t * 64;
        __syncthreads();
        *ldsv(Kt, sr0, scb) = rk0;
        *ldsv(Kt, sr1, scb) = rk1;
        *ldsv(Vs, sr0, scb) = rv0;
        *ldsv(Vs, sr1, scb) = rv1;
        __syncthreads();
        if (t + 1 < nt) {
            const int nn = n0 + 64;
            rk0 = *reinterpret_cast<const bf16x8*>(&Kh[(size_t)(nn + sr0) * DK + scs]);
            rk1 = *reinterpret_cast<const bf16x8*>(&Kh[(size_t)(nn + sr1) * DK + scs]);
            rv0 = *reinterpret_cast<const bf16x8*>(&Vh[(size_t)sr0 * T_SEQ + nn + scs]);
            rv1 = *reinterpret_cast<const bf16x8*>(&Vh[(size_t)sr1 * T_SEQ + nn + scs]);
        }

        f32x4 s[4];
#pragma unroll
        for (int f = 0; f < 4; ++f) {
            bf16x8 kf0 = *ldsv(Kt, 16 * f + li, lg * 16);
            bf16x8 kf1 = *ldsv(Kt, 16 * f + li, 64 + lg * 16);
            s[f] = __builtin_amdgcn_mfma_f32_16x16x32_bf16(kf0, qf0, zero, 0, 0, 0);
            s[f] = __builtin_amdgcn_mfma_f32_16x16x32_bf16(kf1, qf1, s[f], 0, 0, 0);
        }
        float sv[16];
        const bool need_mask = (n0 + 63 > q0);
#pragma unroll
        for (int f = 0; f < 4; ++f)
#pragma unroll
            for (int r = 0; r < 4; ++r) {
                float v = s[f][r] * SCL;
                if (need_mask) {
                    int kv = n0 + 16 * f + lg * 4 + r;
                    if (kv > q0 + li) v = -3.0e38f;
                }
                sv[f * 4 + r] = v;
            }
        float mx = fmaxf(fmaxf(fmaxf(sv[0], sv[1]), fmaxf(sv[2], sv[3])),
                         fmaxf(fmaxf(sv[4], sv[5]), fmaxf(sv[6], sv[7])));
        float mx2 = fmaxf(fmaxf(fmaxf(sv[8], sv[9]), fmaxf(sv[10], sv[11])),
                          fmaxf(fmaxf(sv[12], sv[13]), fmaxf(sv[14], sv[15])));
        float tm = fmaxf(mx, mx2);
        tm = fmaxf(tm, __shfl_xor(tm, 16));
        tm = fmaxf(tm, __shfl_xor(tm, 32));
        float mnew = fmaxf(m, tm);
        float ps[16];
#pragma unroll
        for (int i = 0; i < 16; ++i) ps[i] = __builtin_amdgcn_exp2f(sv[i] - mnew);
        float rs = ((ps[0] + ps[1]) + (ps[2] + ps[3])) + ((ps[4] + ps[5]) + (ps[6] + ps[7]));
        rs += ((ps[8] + ps[9]) + (ps[10] + ps[11])) + ((ps[12] + ps[13]) + (ps[14] + ps[15]));
        rs += __shfl_xor(rs, 16);
        rs += __shfl_xor(rs, 32);
        if (__any(mnew > m)) {
            float alpha = __builtin_amdgcn_exp2f(m - mnew);
            lsum = lsum * alpha + rs;
#pragma unroll
            for (int r = 0; r < 4; ++r) {
                float ar = __shfl(alpha, lg * 4 + r);
#pragma unroll
                for (int cbq = 0; cbq < 4; ++cbq) oacc[cbq][r] *= ar;
            }
        } else {
            lsum += rs;
        }
        m = mnew;
#pragma unroll
        for (int f = 0; f < 4; ++f) {
            unsigned p01, p23;
            asm("v_cvt_pk_bf16_f32 %0, %1, %2" : "=v"(p01) : "v"(ps[4 * f + 0]), "v"(ps[4 * f + 1]));
            asm("v_cvt_pk_bf16_f32 %0, %1, %2" : "=v"(p23) : "v"(ps[4 * f + 2]), "v"(ps[4 * f + 3]));
            unsigned long long pp = ((unsigned long long)p23 << 32) | (unsigned long long)p01;
            *reinterpret_cast<unsigned long long*>(
                (char*)Pw + li * 128 + ((32 * f + lg * 8) ^ ((li & 7) << 4))) = pp;
        }
        bf16x8 pf0 = *ldsv(Pw, li, lg * 16);
        bf16x8 pf1 = *ldsv(Pw, li, 64 + lg * 16);
#pragma unroll
        for (int cbq = 0; cbq < 4; ++cbq) {
            bf16x8 vf0 = *ldsv(Vs, cbq * 16 + li, lg * 16);
            bf16x8 vf1 = *ldsv(Vs, cbq * 16 + li, 64 + lg * 16);
            oacc[cbq] = __builtin_amdgcn_mfma_f32_16x16x32_bf16(pf0, vf0, oacc[cbq], 0, 0, 0);
            oacc[cbq] = __builtin_amdgcn_mfma_f32_16x16x32_bf16(pf1, vf1, oacc[cbq], 0, 0, 0);
        }
    }

    // epilogue: normalize, write Cc in TILED layout for gemm_out staging
    const int b = bh >> 4, h = bh & 15;
#pragma unroll
    for (int r = 0; r < 4; ++r) {
        float lr = __shfl(lsum, lg * 4 + r);
        float inv = 1.0f / lr;
        const int mg = b * T_SEQ + q0 + lg * 4 + r;
        const int mb = mg >> 7, row = mg & 127;
#pragma unroll
        for (int cbq = 0; cbq < 4; ++cbq) {
            const int kb = h * 2 + (cbq >> 1);
            const int kblk = ((cbq & 1) << 1) | (li >> 3);
            Cc[((size_t)(mb * 32 + kb)) * 4096 + kblk * 1024 + row * 8 + (li & 7)] =
                f2b(oacc[cbq][r] * inv);
        }
    }
}

// ---------------- GEMM2: out = concat * W_out^T (fp32 store) ----------------
// 128x64 tile, 4 waves (2x2), tiled inputs, same pipeline as gemm_qkv.
__global__ __launch_bounds__(256, 3) void gemm_out(const short* __restrict__ ab,
                                                   const short* __restrict__ wb,
                                                   float* __restrict__ out) {
    __shared__ short As[2][4096];
    __shared__ short Bs[2][2048];
    const int tid = threadIdx.x;
    const int w = tid >> 6, l = tid & 63, lg = l >> 4, li = l & 15;
    const int wr = w >> 1, wc = w & 1;
    const int bn = blockIdx.x * 64, bm = blockIdx.y * 128;

    const short* pA = ab + (size_t)blockIdx.y * 32 * 4096 + (w * 128 + l) * 8;
    const short* pB = wb + (size_t)blockIdx.x * 32 * 2048 + (w * 64 + l) * 8;

    f32x4 zero = {0.f, 0.f, 0.f, 0.f};
    f32x4 acc[4][2];
#pragma unroll
    for (int m = 0; m < 4; ++m)
#pragma unroll
        for (int n = 0; n < 2; ++n) acc[m][n] = zero;

    gll16(pA,       &As[0][w * 1024]);
    gll16(pA + 512, &As[0][w * 1024 + 512]);
    gll16(pB,       &Bs[0][w * 512]);
    __syncthreads();

    for (int t = 0; t < 32; ++t) {
        if (t < 31) {
            const int nb = (t + 1) & 1;
            gll16(pA + (size_t)(t + 1) * 4096,       &As[nb][w * 1024]);
            gll16(pA + (size_t)(t + 1) * 4096 + 512, &As[nb][w * 1024 + 512]);
            gll16(pB + (size_t)(t + 1) * 2048,       &Bs[nb][w * 512]);
        }
        const int cb = t & 1;
        bf16x8 a[4], b[2];
#pragma unroll
        for (int m = 0; m < 4; ++m)
            a[m] = *reinterpret_cast<const bf16x8*>(&As[cb][lg * 1024 + (wr * 64 + m * 16 + li) * 8]);
#pragma unroll
        for (int n = 0; n < 2; ++n)
            b[n] = *reinterpret_cast<const bf16x8*>(&Bs[cb][lg * 512 + (wc * 32 + n * 16 + li) * 8]);
#pragma unroll
        for (int m = 0; m < 4; ++m)
#pragma unroll
            for (int n = 0; n < 2; ++n)
                acc[m][n] = __builtin_amdgcn_mfma_f32_16x16x32_bf16(a[m], b[n], acc[m][n], 0, 0, 0);
        __syncthreads();
    }

#pragma unroll
    for (int m = 0; m < 4; ++m)
#pragma unroll
        for (int n = 0; n < 2; ++n)
#pragma unroll
            for (int r = 0; r < 4; ++r) {
                const int mi = bm + wr * 64 + m * 16 + lg * 4 + r;
                out[(size_t)mi * D_MODEL + bn + wc * 32 + n * 16 + li] = acc[m][n][r];
            }
}

extern "C" void kernel_launch(void* const* d_in, const int* in_sizes, int n_in,
                              void* d_out, int out_size, void* d_ws, size_t ws_size,
                              hipStream_t stream) {
    const float* x    = (const float*)d_in[0];
    const int*   pos  = (const int*)d_in[1];
    const float* wqkv = (const float*)d_in[2];
    const float* wout = (const float*)d_in[3];
    float* out = (float*)d_out;

    char* ws = (char*)d_ws;
    size_t off = 0;
    short* xb  = (short*)(ws + off); off += (size_t)4096 * 1024 * 2;
    short* wqb = (short*)(ws + off); off += (size_t)3072 * 1024 * 2;
    short* wob = (short*)(ws + off); off += (size_t)1024 * 1024 * 2;
    short* Q   = (short*)(ws + off); off += (size_t)32 * 2048 * 64 * 2;
    short* Kb  = (short*)(ws + off); off += (size_t)32 * 2048 * 64 * 2;
    short* Vt  = (short*)(ws + off); off += (size_t)32 * 64 * 2048 * 2;
    off += 4096;
    short* Cc  = (short*)(ws + off); off += (size_t)4096 * 1024 * 2;
    float* ct  = (float*)(ws + off); off += (size_t)4096 * 32 * 4;
    float* st  = (float*)(ws + off); off += (size_t)4096 * 32 * 4;

    cvt_all<<<4096, 256, 0, stream>>>(x, wqkv, wout, xb, wqb, wob);
    rope_table<<<512, 256, 0, stream>>>(pos, ct, st);
    gemm_qkv<<<dim3(24, 32), 256, 0, stream>>>(xb, wqb, ct, st, Q, Kb, Vt);
    attn<<<1024, 256, 0, stream>>>(Q, Kb, Vt, Cc);
    gemm_out<<<dim3(16, 32), 256, 0, stream>>>(Cc, wob, out);
}

// Round 6
// 132.491 us; speedup vs baseline: 2.5823x; 1.1528x over previous
//
#include <hip/hip_runtime.h>
#include <hip/hip_bf16.h>
#include <cmath>

#define T_SEQ 2048
#define D_MODEL 1024
#define NHEAD 16
#define DK 64

typedef short bf16x8 __attribute__((ext_vector_type(8)));
typedef float f32x4 __attribute__((ext_vector_type(4)));
typedef float f32x16 __attribute__((ext_vector_type(16)));
typedef unsigned uint2v __attribute__((ext_vector_type(2)));

union U8 { unsigned u[4]; bf16x8 v; };

// RNE float -> bf16 (finite inputs only)
__device__ __forceinline__ short f2b(float f) {
    unsigned u = __builtin_bit_cast(unsigned, f);
    unsigned r = (u + 0x7FFFu + ((u >> 16) & 1u)) >> 16;
    return (short)r;
}

// async global->LDS, 16B per lane; lds base wave-uniform (HW adds lane*16)
__device__ __forceinline__ void gll16(const void* g, void* l) {
    __builtin_amdgcn_global_load_lds(
        (__attribute__((address_space(1))) void*)g,
        (__attribute__((address_space(3))) void*)l, 16, 0, 0);
}

// XOR-swizzled LDS frag read: row stride 128B, 16B chunk index 0..7
__device__ __forceinline__ bf16x8 lds_frag(const short* base, int row, int chunk) {
    return *reinterpret_cast<const bf16x8*>(
        (const char*)base + row * 128 + ((chunk * 16) ^ ((row & 7) << 4)));
}

__device__ __forceinline__ unsigned pkbf16(float a, float b) {
    unsigned r;
    asm("v_cvt_pk_bf16_f32 %0, %1, %2" : "=v"(r) : "v"(a), "v"(b));
    return r;
}
__device__ __forceinline__ void pl32swap(unsigned& a, unsigned& b) {
    uint2v r = __builtin_amdgcn_permlane32_swap(a, b, false, false);
    a = r.x; b = r.y;
}

// ================= fused fp32 -> bf16 convert into TILED layouts =================
__global__ __launch_bounds__(256) void cvt_all(const float* __restrict__ x,
                                               const float* __restrict__ wq,
                                               const float* __restrict__ wo,
                                               short* __restrict__ xb,
                                               short* __restrict__ wqb,
                                               short* __restrict__ wob) {
    int i = blockIdx.x * 256 + threadIdx.x;
    const float* src;
    short* dst;
    int srcoff, c;
    if (i < 524288) {
        c = i;
        int tile = c >> 9, cc = c & 511;
        int kblk = cc >> 7, row = cc & 127;
        int rb = tile >> 5, kb = tile & 31;
        srcoff = (rb * 128 + row) * D_MODEL + kb * 32 + kblk * 8;
        src = x; dst = xb;
    } else if (i < 917504) {
        c = i - 524288;
        int tile = c >> 9, cc = c & 511;
        int kblk = cc >> 7, row = cc & 127;
        int rb = tile >> 5, kb = tile & 31;
        srcoff = (rb * 128 + row) * D_MODEL + kb * 32 + kblk * 8;
        src = wq; dst = wqb;
    } else {
        c = i - 917504;
        int tile = c >> 8, cc = c & 255;
        int kblk = cc >> 6, row = cc & 63;
        int nb = tile >> 5, kb = tile & 31;
        srcoff = (nb * 64 + row) * D_MODEL + kb * 32 + kblk * 8;
        src = wo; dst = wob;
    }
    float4 a = *reinterpret_cast<const float4*>(src + srcoff);
    float4 b = *reinterpret_cast<const float4*>(src + srcoff + 4);
    bf16x8 v;
    v[0] = f2b(a.x); v[1] = f2b(a.y); v[2] = f2b(a.z); v[3] = f2b(a.w);
    v[4] = f2b(b.x); v[5] = f2b(b.y); v[6] = f2b(b.z); v[7] = f2b(b.w);
    reinterpret_cast<bf16x8*>(dst)[c] = v;
}

// ---------------- RoPE cos/sin tables: (B*T, 32) ----------------
__global__ __launch_bounds__(256) void rope_table(const int* __restrict__ pos,
                                                  float* __restrict__ ct,
                                                  float* __restrict__ st) {
    int i = blockIdx.x * blockDim.x + threadIdx.x;
    int bt = i >> 5, n = i & 31;
    float p = (float)pos[bt];
    float invf = expf((float)n * (-2.0f / (float)DK) * 9.210340371976184f);
    float ang = p * invf;
    float s, c;
    sincosf(ang, &s, &c);
    ct[i] = c; st[i] = s;
}

// ---------------- GEMM1: qkv = x * W_qkv^T, fused RoPE, scatter ----------------
__global__ __launch_bounds__(256, 3) void gemm_qkv(const short* __restrict__ xb,
                                                   const short* __restrict__ wb,
                                                   const float* __restrict__ ct,
                                                   const float* __restrict__ st,
                                                   short* __restrict__ Qo,
                                                   short* __restrict__ Ko,
                                                   short* __restrict__ Vt) {
    __shared__ short As[2][4096];
    __shared__ short Bs[2][4096];
    const int tid = threadIdx.x;
    const int w = tid >> 6, l = tid & 63, lg = l >> 4, li = l & 15;
    const int wr = w >> 1, wc = w & 1;
    const int bn = blockIdx.x * 128, bm = blockIdx.y * 128;

    const short* pA = xb + (size_t)blockIdx.y * 32 * 4096 + (w * 128 + l) * 8;
    const short* pB = wb + (size_t)blockIdx.x * 32 * 4096 + (w * 128 + l) * 8;

    f32x4 zero = {0.f, 0.f, 0.f, 0.f};
    f32x4 acc[4][4];
#pragma unroll
    for (int m = 0; m < 4; ++m)
#pragma unroll
        for (int n = 0; n < 4; ++n) acc[m][n] = zero;

    gll16(pA,       &As[0][w * 1024]);
    gll16(pA + 512, &As[0][w * 1024 + 512]);
    gll16(pB,       &Bs[0][w * 1024]);
    gll16(pB + 512, &Bs[0][w * 1024 + 512]);
    __syncthreads();

    for (int t = 0; t < 32; ++t) {
        if (t < 31) {
            const int nb = (t + 1) & 1;
            const size_t ko = (size_t)(t + 1) * 4096;
            gll16(pA + ko,       &As[nb][w * 1024]);
            gll16(pA + ko + 512, &As[nb][w * 1024 + 512]);
            gll16(pB + ko,       &Bs[nb][w * 1024]);
            gll16(pB + ko + 512, &Bs[nb][w * 1024 + 512]);
        }
        const int cb = t & 1;
        bf16x8 a[4], b[4];
#pragma unroll
        for (int m = 0; m < 4; ++m)
            a[m] = *reinterpret_cast<const bf16x8*>(&As[cb][lg * 1024 + (wr * 64 + m * 16 + li) * 8]);
#pragma unroll
        for (int n = 0; n < 4; ++n)
            b[n] = *reinterpret_cast<const bf16x8*>(&Bs[cb][lg * 1024 + (wc * 64 + n * 16 + li) * 8]);
#pragma unroll
        for (int m = 0; m < 4; ++m)
#pragma unroll
            for (int n = 0; n < 4; ++n)
                acc[m][n] = __builtin_amdgcn_mfma_f32_16x16x32_bf16(a[m], b[n], acc[m][n], 0, 0, 0);
        __syncthreads();
    }

    const int which = bn >> 10;                 // 0:q 1:k 2:v
    const int h = ((bn >> 6) + wc) & 15;
#pragma unroll
    for (int n = 0; n < 4; ++n) {
        const int d = n * 16 + li;
#pragma unroll
        for (int m = 0; m < 4; ++m)
#pragma unroll
            for (int r = 0; r < 4; ++r) {
                const int mi = bm + wr * 64 + m * 16 + lg * 4 + r;   // = b*T + t
                const int b_ = mi >> 11, tt = mi & (T_SEQ - 1);
                float v = acc[m][n][r];
                if (which == 2) {
                    Vt[((size_t)((b_ * NHEAD + h) * DK + d)) * T_SEQ + tt] = f2b(v);
                } else {
                    float vp = __shfl_xor(v, 1);
                    int nn = n * 8 + (li >> 1);
                    float c = ct[(size_t)mi * 32 + nn];
                    float s = st[(size_t)mi * 32 + nn];
                    float o = (d & 1) ? (v * c + vp * s) : (v * c - vp * s);
                    if (which == 0) o *= 0.18033688011112042f;   // (1/8)*log2(e) pre-scale
                    short* dst = (which == 0) ? Qo : Ko;
                    dst[((size_t)((b_ * NHEAD + h) * T_SEQ + tt)) * DK + d] = f2b(o);
                }
            }
    }
}

// ---------------- flash attention (causal), 32x32 MFMA, in-register P ----------------
// 512 blocks; block -> (bh, qtile of 128 rows) with work-balanced pairing.
// 4 waves; wave w owns q rows [blkq0 + 32w, +32). KVBLK = 64; K/V staged via
// global_load_lds with pre-swizzled source; P redistribution via cvt_pk + permlane32_swap.
__global__ __launch_bounds__(256, 3) void attn(const short* __restrict__ Q,
                                               const short* __restrict__ K,
                                               const short* __restrict__ Vt,
                                               short* __restrict__ Cc) {
    __shared__ short Kls[2][4096];
    __shared__ short Vls[2][4096];

    const int bid = blockIdx.x;
    const int ii = bid & 255, rr = bid >> 8;
    const int bh = ii & 31;
    const int qt = rr ? (15 - (ii >> 5)) : (ii >> 5);
    const int blkq0 = qt * 128;
    const int ntb = 2 * qt + 2;

    const int tid = threadIdx.x;
    const int w = tid >> 6, l = tid & 63;
    const int l31 = l & 31, hi = l >> 5, hi4 = hi * 4, hi8 = hi * 8;
    const int q0w = blkq0 + w * 32;

    const short* Qh = Q + (size_t)bh * T_SEQ * DK;
    const short* Kh = K + (size_t)bh * T_SEQ * DK;
    const short* Vh = Vt + (size_t)bh * DK * T_SEQ;

    // Q as B-operand fragments: qf[ks] = Q[q0w + l31][ks*16 + hi8 .. +8]
    bf16x8 qf[4];
#pragma unroll
    for (int ks = 0; ks < 4; ++ks)
        qf[ks] = *reinterpret_cast<const bf16x8*>(&Qh[(size_t)(q0w + l31) * DK + ks * 16 + hi8]);

    f32x16 o0 = {0.f,0.f,0.f,0.f,0.f,0.f,0.f,0.f,0.f,0.f,0.f,0.f,0.f,0.f,0.f,0.f};
    f32x16 o1 = o0;
    float m = -3.0e38f;
    float lsum = 0.f;

    // staging: wave w stages chunks (2w+jj)*64 + lane of each 8KB tile; source
    // column pre-XOR-permuted so linear LDS + swizzled reads line up (rule #21)
    const int c0 = (2 * w) * 64 + l;
    const int c1 = c0 + 64;
    const int r0 = c0 >> 3, cc0 = (c0 & 7) ^ (r0 & 7);
    const int r1 = c1 >> 3, cc1 = (c1 & 7) ^ (r1 & 7);

#define STAGE(buf, n0_)                                                        \
    do {                                                                       \
        gll16(Kh + (size_t)((n0_) + r0) * DK + cc0 * 8, &Kls[buf][(2 * w) * 512]);      \
        gll16(Kh + (size_t)((n0_) + r1) * DK + cc1 * 8, &Kls[buf][(2 * w + 1) * 512]);  \
        gll16(Vh + (size_t)r0 * T_SEQ + (n0_) + cc0 * 8, &Vls[buf][(2 * w) * 512]);     \
        gll16(Vh + (size_t)r1 * T_SEQ + (n0_) + cc1 * 8, &Vls[buf][(2 * w + 1) * 512]); \
    } while (0)

    STAGE(0, 0);
    __syncthreads();

    for (int t = 0; t < ntb; ++t) {
        const int n0 = t * 64;
        if (t + 1 < ntb) STAGE((t + 1) & 1, (t + 1) * 64);

        if (n0 < q0w + 32) {
            const short* Kc = Kls[t & 1];
            const short* Vc = Vls[t & 1];

            // ---- QK^T: S^T fragments, q = l31, kv = kb*32 + (r&3)+8*(r>>2)+hi4
            f32x16 s0 = {0.f,0.f,0.f,0.f,0.f,0.f,0.f,0.f,0.f,0.f,0.f,0.f,0.f,0.f,0.f,0.f};
            f32x16 s1 = s0;
            __builtin_amdgcn_s_setprio(1);
#pragma unroll
            for (int ks = 0; ks < 4; ++ks) {
                bf16x8 kf0 = lds_frag(Kc, l31,      ks * 2 + hi);
                bf16x8 kf1 = lds_frag(Kc, 32 + l31, ks * 2 + hi);
                s0 = __builtin_amdgcn_mfma_f32_32x32x16_bf16(kf0, qf[ks], s0, 0, 0, 0);
                s1 = __builtin_amdgcn_mfma_f32_32x32x16_bf16(kf1, qf[ks], s1, 0, 0, 0);
            }
            __builtin_amdgcn_s_setprio(0);

            float p[32];
#pragma unroll
            for (int r = 0; r < 16; ++r) { p[r] = s0[r]; p[16 + r] = s1[r]; }

            // ---- causal mask (only the wave's last tile)
            if (n0 + 64 > q0w) {
                const int qrel = q0w + l31 - n0;
#pragma unroll
                for (int r = 0; r < 16; ++r) {
                    const int kvm = (r & 3) + 8 * (r >> 2) + hi4;
                    if (kvm > qrel) p[r] = -3.0e38f;
                    if (kvm + 32 > qrel) p[16 + r] = -3.0e38f;
                }
            }

            // ---- row max: 31-op tree + one cross-half exchange
            float t16[16];
#pragma unroll
            for (int r = 0; r < 16; ++r) t16[r] = fmaxf(p[r], p[16 + r]);
#pragma unroll
            for (int d = 8; d >= 1; d >>= 1)
#pragma unroll
                for (int r = 0; r < 8; ++r)
                    if (r < d) t16[r] = fmaxf(t16[r], t16[r + d]);
            float tmax = fmaxf(t16[0], __shfl_xor(t16[0], 32));

            // ---- defer-rescale (T13): rescale O only when max grows past THR
            if (__any(tmax > m + 8.0f)) {
                float mnew = fmaxf(m, tmax);
                float alpha = __builtin_amdgcn_exp2f(m - mnew);
                m = mnew;
#pragma unroll
                for (int r = 0; r < 16; ++r) {
                    float ar = __shfl(alpha, (r & 3) + 8 * (r >> 2) + hi4);
                    o0[r] *= ar; o1[r] *= ar;
                }
                lsum *= alpha;
            }

            // ---- P = exp2(S - m), row sum tree + exchange
#pragma unroll
            for (int r = 0; r < 32; ++r) p[r] = __builtin_amdgcn_exp2f(p[r] - m);
            float a16[16];
#pragma unroll
            for (int r = 0; r < 16; ++r) a16[r] = p[r] + p[16 + r];
#pragma unroll
            for (int d = 8; d >= 1; d >>= 1)
#pragma unroll
                for (int r = 0; r < 8; ++r)
                    if (r < d) a16[r] += a16[r + d];
            lsum += a16[0] + __shfl_xor(a16[0], 32);

            // ---- PV: build A-frags in-register (T12), V from LDS
            __builtin_amdgcn_s_setprio(1);
#pragma unroll
            for (int kb = 0; kb < 2; ++kb) {
                unsigned pk0 = pkbf16(p[kb * 16 + 0],  p[kb * 16 + 1]);
                unsigned pk1 = pkbf16(p[kb * 16 + 2],  p[kb * 16 + 3]);
                unsigned pk2 = pkbf16(p[kb * 16 + 4],  p[kb * 16 + 5]);
                unsigned pk3 = pkbf16(p[kb * 16 + 6],  p[kb * 16 + 7]);
                unsigned pk4 = pkbf16(p[kb * 16 + 8],  p[kb * 16 + 9]);
                unsigned pk5 = pkbf16(p[kb * 16 + 10], p[kb * 16 + 11]);
                unsigned pk6 = pkbf16(p[kb * 16 + 12], p[kb * 16 + 13]);
                unsigned pk7 = pkbf16(p[kb * 16 + 14], p[kb * 16 + 15]);
                pl32swap(pk0, pk2); pl32swap(pk1, pk3);
                pl32swap(pk4, pk6); pl32swap(pk5, pk7);
                U8 f0, f1;
                f0.u[0] = pk0; f0.u[1] = pk1; f0.u[2] = pk2; f0.u[3] = pk3;
                f1.u[0] = pk4; f1.u[1] = pk5; f1.u[2] = pk6; f1.u[3] = pk7;
                bf16x8 v00 = lds_frag(Vc, l31,      kb * 4 + hi);
                bf16x8 v01 = lds_frag(Vc, l31,      kb * 4 + 2 + hi);
                bf16x8 v10 = lds_frag(Vc, 32 + l31, kb * 4 + hi);
                bf16x8 v11 = lds_frag(Vc, 32 + l31, kb * 4 + 2 + hi);
                o0 = __builtin_amdgcn_mfma_f32_32x32x16_bf16(f0.v, v00, o0, 0, 0, 0);
                o0 = __builtin_amdgcn_mfma_f32_32x32x16_bf16(f1.v, v01, o0, 0, 0, 0);
                o1 = __builtin_amdgcn_mfma_f32_32x32x16_bf16(f0.v, v10, o1, 0, 0, 0);
                o1 = __builtin_amdgcn_mfma_f32_32x32x16_bf16(f1.v, v11, o1, 0, 0, 0);
            }
            __builtin_amdgcn_s_setprio(0);
        }
        __syncthreads();
    }

    // ---- epilogue: normalize, write Cc in TILED layout for gemm_out staging
    const int b = bh >> 4, h = bh & 15;
    const float linv = 1.0f / lsum;
#pragma unroll
    for (int r = 0; r < 16; ++r) {
        const int qoff = (r & 3) + 8 * (r >> 2) + hi4;
        float inv = __shfl(linv, qoff);
        const int mg = b * T_SEQ + q0w + qoff;
        const int mb = mg >> 7, row = mg & 127;
        const int kblk = (l31 >> 3) & 3, el = l & 7;
        Cc[((size_t)(mb * 32 + h * 2 + 0)) * 4096 + kblk * 1024 + row * 8 + el] = f2b(o0[r] * inv);
        Cc[((size_t)(mb * 32 + h * 2 + 1)) * 4096 + kblk * 1024 + row * 8 + el] = f2b(o1[r] * inv);
    }
}

// ---------------- GEMM2: out = concat * W_out^T (fp32 store) ----------------
__global__ __launch_bounds__(256, 3) void gemm_out(const short* __restrict__ ab,
                                                   const short* __restrict__ wb,
                                                   float* __restrict__ out) {
    __shared__ short As[2][4096];
    __shared__ short Bs[2][2048];
    const int tid = threadIdx.x;
    const int w = tid >> 6, l = tid & 63, lg = l >> 4, li = l & 15;
    const int wr = w >> 1, wc = w & 1;
    const int bn = blockIdx.x * 64, bm = blockIdx.y * 128;

    const short* pA = ab + (size_t)blockIdx.y * 32 * 4096 + (w * 128 + l) * 8;
    const short* pB = wb + (size_t)blockIdx.x * 32 * 2048 + (w * 64 + l) * 8;

    f32x4 zero = {0.f, 0.f, 0.f, 0.f};
    f32x4 acc[4][2];
#pragma unroll
    for (int m = 0; m < 4; ++m)
#pragma unroll
        for (int n = 0; n < 2; ++n) acc[m][n] = zero;

    gll16(pA,       &As[0][w * 1024]);
    gll16(pA + 512, &As[0][w * 1024 + 512]);
    gll16(pB,       &Bs[0][w * 512]);
    __syncthreads();

    for (int t = 0; t < 32; ++t) {
        if (t < 31) {
            const int nb = (t + 1) & 1;
            gll16(pA + (size_t)(t + 1) * 4096,       &As[nb][w * 1024]);
            gll16(pA + (size_t)(t + 1) * 4096 + 512, &As[nb][w * 1024 + 512]);
            gll16(pB + (size_t)(t + 1) * 2048,       &Bs[nb][w * 512]);
        }
        const int cb = t & 1;
        bf16x8 a[4], b[2];
#pragma unroll
        for (int m = 0; m < 4; ++m)
            a[m] = *reinterpret_cast<const bf16x8*>(&As[cb][lg * 1024 + (wr * 64 + m * 16 + li) * 8]);
#pragma unroll
        for (int n = 0; n < 2; ++n)
            b[n] = *reinterpret_cast<const bf16x8*>(&Bs[cb][lg * 512 + (wc * 32 + n * 16 + li) * 8]);
#pragma unroll
        for (int m = 0; m < 4; ++m)
#pragma unroll
            for (int n = 0; n < 2; ++n)
                acc[m][n] = __builtin_amdgcn_mfma_f32_16x16x32_bf16(a[m], b[n], acc[m][n], 0, 0, 0);
        __syncthreads();
    }

#pragma unroll
    for (int m = 0; m < 4; ++m)
#pragma unroll
        for (int n = 0; n < 2; ++n)
#pragma unroll
            for (int r = 0; r < 4; ++r) {
                const int mi = bm + wr * 64 + m * 16 + lg * 4 + r;
                out[(size_t)mi * D_MODEL + bn + wc * 32 + n * 16 + li] = acc[m][n][r];
            }
}

extern "C" void kernel_launch(void* const* d_in, const int* in_sizes, int n_in,
                              void* d_out, int out_size, void* d_ws, size_t ws_size,
                              hipStream_t stream) {
    const float* x    = (const float*)d_in[0];
    const int*   pos  = (const int*)d_in[1];
    const float* wqkv = (const float*)d_in[2];
    const float* wout = (const float*)d_in[3];
    float* out = (float*)d_out;

    char* ws = (char*)d_ws;
    size_t off = 0;
    short* xb  = (short*)(ws + off); off += (size_t)4096 * 1024 * 2;
    short* wqb = (short*)(ws + off); off += (size_t)3072 * 1024 * 2;
    short* wob = (short*)(ws + off); off += (size_t)1024 * 1024 * 2;
    short* Q   = (short*)(ws + off); off += (size_t)32 * 2048 * 64 * 2;
    short* Kb  = (short*)(ws + off); off += (size_t)32 * 2048 * 64 * 2;
    short* Vt  = (short*)(ws + off); off += (size_t)32 * 64 * 2048 * 2;
    off += 4096;
    short* Cc  = (short*)(ws + off); off += (size_t)4096 * 1024 * 2;
    float* ct  = (float*)(ws + off); off += (size_t)4096 * 32 * 4;
    float* st  = (float*)(ws + off); off += (size_t)4096 * 32 * 4;

    cvt_all<<<4096, 256, 0, stream>>>(x, wqkv, wout, xb, wqb, wob);
    rope_table<<<512, 256, 0, stream>>>(pos, ct, st);
    gemm_qkv<<<dim3(24, 32), 256, 0, stream>>>(xb, wqb, ct, st, Q, Kb, Vt);
    attn<<<512, 256, 0, stream>>>(Q, Kb, Vt, Cc);
    gemm_out<<<dim3(16, 32), 256, 0, stream>>>(Cc, wob, out);
}

// Round 7
// 114.320 us; speedup vs baseline: 2.9927x; 1.1589x over previous
//
#include <hip/hip_runtime.h>
#include <hip/hip_bf16.h>
#include <cmath>

#define T_SEQ 2048
#define D_MODEL 1024
#define NHEAD 16
#define DK 64

typedef short bf16x8 __attribute__((ext_vector_type(8)));
typedef float f32x4 __attribute__((ext_vector_type(4)));
typedef float f32x16 __attribute__((ext_vector_type(16)));
typedef unsigned uint2v __attribute__((ext_vector_type(2)));

union U8 { unsigned u[4]; bf16x8 v; };

#define VMCNT(n) asm volatile("s_waitcnt vmcnt(" #n ")" ::: "memory")
#define BAR() __builtin_amdgcn_s_barrier()
#define SFENCE() __builtin_amdgcn_sched_barrier(0)

// RNE float -> bf16 (finite inputs only)
__device__ __forceinline__ short f2b(float f) {
    unsigned u = __builtin_bit_cast(unsigned, f);
    unsigned r = (u + 0x7FFFu + ((u >> 16) & 1u)) >> 16;
    return (short)r;
}

// async global->LDS, 16B per lane; lds base wave-uniform (HW adds lane*16)
__device__ __forceinline__ void gll16(const void* g, void* l) {
    __builtin_amdgcn_global_load_lds(
        (__attribute__((address_space(1))) void*)g,
        (__attribute__((address_space(3))) void*)l, 16, 0, 0);
}

// XOR-swizzled LDS frag read: row stride 128B, 16B chunk index 0..7
__device__ __forceinline__ bf16x8 lds_frag(const short* base, int row, int chunk) {
    return *reinterpret_cast<const bf16x8*>(
        (const char*)base + row * 128 + ((chunk * 16) ^ ((row & 7) << 4)));
}

__device__ __forceinline__ unsigned pkbf16(float a, float b) {
    unsigned r;
    asm("v_cvt_pk_bf16_f32 %0, %1, %2" : "=v"(r) : "v"(a), "v"(b));
    return r;
}
__device__ __forceinline__ void pl32swap(unsigned& a, unsigned& b) {
    uint2v r = __builtin_amdgcn_permlane32_swap(a, b, false, false);
    a = r.x; b = r.y;
}

// ====== fused fp32->bf16 convert into TILED layouts + RoPE table (one launch) ======
__global__ __launch_bounds__(256) void cvt_all(const float* __restrict__ x,
                                               const float* __restrict__ wq,
                                               const float* __restrict__ wo,
                                               const int* __restrict__ pos,
                                               short* __restrict__ xb,
                                               short* __restrict__ wqb,
                                               short* __restrict__ wob,
                                               float* __restrict__ ct,
                                               float* __restrict__ st) {
    int i = blockIdx.x * 256 + threadIdx.x;
    if (i >= 1048576) {                 // RoPE table: 131072 entries
        int j = i - 1048576;
        int bt = j >> 5, n = j & 31;
        float p = (float)pos[bt];
        float invf = expf((float)n * (-2.0f / (float)DK) * 9.210340371976184f);
        float s, c;
        sincosf(p * invf, &s, &c);
        ct[j] = c; st[j] = s;
        return;
    }
    const float* src;
    short* dst;
    int srcoff, c;
    if (i < 524288) {                 // xb: 32 rb x 32 kb tiles (128-row)
        c = i;
        int tile = c >> 9, cc = c & 511;
        int kblk = cc >> 7, row = cc & 127;
        int rb = tile >> 5, kb = tile & 31;
        srcoff = (rb * 128 + row) * D_MODEL + kb * 32 + kblk * 8;
        src = x; dst = xb;
    } else if (i < 917504) {          // wqb: 24 nb x 32 kb tiles (128-row)
        c = i - 524288;
        int tile = c >> 9, cc = c & 511;
        int kblk = cc >> 7, row = cc & 127;
        int rb = tile >> 5, kb = tile & 31;
        srcoff = (rb * 128 + row) * D_MODEL + kb * 32 + kblk * 8;
        src = wq; dst = wqb;
    } else {                          // wob: 16 nb x 32 kb tiles (64-row)
        c = i - 917504;
        int tile = c >> 8, cc = c & 255;
        int kblk = cc >> 6, row = cc & 63;
        int nb = tile >> 5, kb = tile & 31;
        srcoff = (nb * 64 + row) * D_MODEL + kb * 32 + kblk * 8;
        src = wo; dst = wob;
    }
    float4 a = *reinterpret_cast<const float4*>(src + srcoff);
    float4 b = *reinterpret_cast<const float4*>(src + srcoff + 4);
    bf16x8 v;
    v[0] = f2b(a.x); v[1] = f2b(a.y); v[2] = f2b(a.z); v[3] = f2b(a.w);
    v[4] = f2b(b.x); v[5] = f2b(b.y); v[6] = f2b(b.z); v[7] = f2b(b.w);
    reinterpret_cast<bf16x8*>(dst)[c] = v;
}

// ---------------- GEMM1: qkv = x * W_qkv^T, fused RoPE, scatter ----------------
// 128x128 tile, 4 waves (2x2), BK=32, 3-buffer LDS ring, counted vmcnt (T4),
// V written via LDS transpose (coalesced 128B rows).
__global__ __launch_bounds__(256, 3) void gemm_qkv(const short* __restrict__ xb,
                                                   const short* __restrict__ wb,
                                                   const float* __restrict__ ct,
                                                   const float* __restrict__ st,
                                                   short* __restrict__ Qo,
                                                   short* __restrict__ Ko,
                                                   short* __restrict__ Vt) {
    __shared__ short SM[3][8192];   // [buf][ A:0..4096 | B:4096..8192 ]
    const int tid = threadIdx.x;
    const int w = tid >> 6, l = tid & 63, lg = l >> 4, li = l & 15;
    const int wr = w >> 1, wc = w & 1;
    const int bn = blockIdx.x * 128, bm = blockIdx.y * 128;

    const short* pA = xb + (size_t)blockIdx.y * 32 * 4096 + (w * 128 + l) * 8;
    const short* pB = wb + (size_t)blockIdx.x * 32 * 4096 + (w * 128 + l) * 8;

    f32x4 zero = {0.f, 0.f, 0.f, 0.f};
    f32x4 acc[4][4];
#pragma unroll
    for (int m = 0; m < 4; ++m)
#pragma unroll
        for (int n = 0; n < 4; ++n) acc[m][n] = zero;

#define GSTAGE(buf, t_)                                               \
    do {                                                              \
        const size_t ko = (size_t)(t_) * 4096;                        \
        gll16(pA + ko,       &SM[buf][w * 1024]);                     \
        gll16(pA + ko + 512, &SM[buf][w * 1024 + 512]);               \
        gll16(pB + ko,       &SM[buf][4096 + w * 1024]);              \
        gll16(pB + ko + 512, &SM[buf][4096 + w * 1024 + 512]);        \
    } while (0)

    GSTAGE(0, 0);
    GSTAGE(1, 1);

    for (int t = 0; t < 32; ++t) {
        if (t < 31) { VMCNT(4); } else { VMCNT(0); }
        BAR();
        SFENCE();
        if (t + 2 < 32) GSTAGE((t + 2) % 3, t + 2);
        const short* Ac = &SM[t % 3][0];
        const short* Bc = &SM[t % 3][4096];
        bf16x8 a[4], b[4];
#pragma unroll
        for (int m = 0; m < 4; ++m)
            a[m] = *reinterpret_cast<const bf16x8*>(&Ac[lg * 1024 + (wr * 64 + m * 16 + li) * 8]);
#pragma unroll
        for (int n = 0; n < 4; ++n)
            b[n] = *reinterpret_cast<const bf16x8*>(&Bc[lg * 1024 + (wc * 64 + n * 16 + li) * 8]);
        __builtin_amdgcn_s_setprio(1);
#pragma unroll
        for (int m = 0; m < 4; ++m)
#pragma unroll
            for (int n = 0; n < 4; ++n)
                acc[m][n] = __builtin_amdgcn_mfma_f32_16x16x32_bf16(a[m], b[n], acc[m][n], 0, 0, 0);
        __builtin_amdgcn_s_setprio(0);
    }
#undef GSTAGE

    const int which = bn >> 10;                 // 0:q 1:k 2:v
    const int h = ((bn >> 6) + wc) & 15;
    if (which == 2) {
        // ---- V: transpose via per-wave 8KB LDS scratch, coalesced Vt writes
        __syncthreads();
        short* scr = &SM[0][0] + w * 4096;      // [d(64)][t(64)] swizzled, 8KB
#pragma unroll
        for (int n = 0; n < 4; ++n)
#pragma unroll
            for (int m = 0; m < 4; ++m)
#pragma unroll
                for (int rp = 0; rp < 2; ++rp) {
                    int d = n * 16 + li;
                    int t64 = m * 16 + lg * 4 + rp * 2;
                    unsigned pk = pkbf16(acc[m][n][rp * 2], acc[m][n][rp * 2 + 1]);
                    *reinterpret_cast<unsigned*>(
                        (char*)scr + ((d * 128 + t64 * 2) ^ ((d & 7) << 4))) = pk;
                }
        const int mi0 = bm + wr * 64;
        const int b0 = mi0 >> 11, t0 = mi0 & (T_SEQ - 1);
        short* vbase = Vt + (size_t)(b0 * NHEAD + h) * DK * T_SEQ + t0;
#pragma unroll
        for (int db = 0; db < 8; ++db) {
            int d = db * 8 + (l >> 3);
            int ch = l & 7;
            bf16x8 v = *reinterpret_cast<const bf16x8*>(
                (char*)scr + ((d * 128 + ch * 16) ^ ((d & 7) << 4)));
            *reinterpret_cast<bf16x8*>(vbase + (size_t)d * T_SEQ + ch * 8) = v;
        }
    } else {
        // ---- Q/K: RoPE epilogue (Q pre-scaled by (1/8)*log2(e))
#pragma unroll
        for (int n = 0; n < 4; ++n) {
            const int d = n * 16 + li;
#pragma unroll
            for (int m = 0; m < 4; ++m)
#pragma unroll
                for (int r = 0; r < 4; ++r) {
                    const int mi = bm + wr * 64 + m * 16 + lg * 4 + r;
                    const int b_ = mi >> 11, tt = mi & (T_SEQ - 1);
                    float v = acc[m][n][r];
                    float vp = __shfl_xor(v, 1);
                    int nn = n * 8 + (li >> 1);
                    float c = ct[(size_t)mi * 32 + nn];
                    float s = st[(size_t)mi * 32 + nn];
                    float o = (d & 1) ? (v * c + vp * s) : (v * c - vp * s);
                    if (which == 0) o *= 0.18033688011112042f;
                    short* dst = (which == 0) ? Qo : Ko;
                    dst[((size_t)((b_ * NHEAD + h) * T_SEQ + tt)) * DK + d] = f2b(o);
                }
        }
    }
}

// ---------------- flash attention (causal), 32x32 MFMA, pipelined staging ----------
__global__ __launch_bounds__(256, 2) void attn(const short* __restrict__ Q,
                                               const short* __restrict__ K,
                                               const short* __restrict__ Vt,
                                               short* __restrict__ Cc) {
    __shared__ short Kls[3][4096];
    __shared__ short Vls[3][4096];

    const int bid = blockIdx.x;
    const int ii = bid & 255, rr = bid >> 8;
    const int bh = ii & 31;
    const int qt = rr ? (15 - (ii >> 5)) : (ii >> 5);
    const int blkq0 = qt * 128;
    const int ntb = 2 * qt + 2;

    const int tid = threadIdx.x;
    const int w = tid >> 6, l = tid & 63;
    const int l31 = l & 31, hi = l >> 5, hi4 = hi * 4, hi8 = hi * 8;
    const int q0w = blkq0 + w * 32;

    const short* Qh = Q + (size_t)bh * T_SEQ * DK;
    const short* Kh = K + (size_t)bh * T_SEQ * DK;
    const short* Vh = Vt + (size_t)bh * DK * T_SEQ;

    bf16x8 qf[4];
#pragma unroll
    for (int ks = 0; ks < 4; ++ks)
        qf[ks] = *reinterpret_cast<const bf16x8*>(&Qh[(size_t)(q0w + l31) * DK + ks * 16 + hi8]);

    f32x16 o0 = {0.f,0.f,0.f,0.f,0.f,0.f,0.f,0.f,0.f,0.f,0.f,0.f,0.f,0.f,0.f,0.f};
    f32x16 o1 = o0;
    float m = -3.0e38f;
    float lsum = 0.f;

    const int c0 = w * 128 + l;
    const int c1 = c0 + 64;
    const int r0 = c0 >> 3, cc0 = (c0 & 7) ^ (r0 & 7);
    const int r1 = c1 >> 3, cc1 = (c1 & 7) ^ (r1 & 7);

#define ASTAGE(buf, n0_)                                                                \
    do {                                                                                \
        gll16(Kh + (size_t)((n0_) + r0) * DK + cc0 * 8, &Kls[buf][(2 * w) * 512]);      \
        gll16(Kh + (size_t)((n0_) + r1) * DK + cc1 * 8, &Kls[buf][(2 * w + 1) * 512]);  \
        gll16(Vh + (size_t)r0 * T_SEQ + (n0_) + cc0 * 8, &Vls[buf][(2 * w) * 512]);     \
        gll16(Vh + (size_t)r1 * T_SEQ + (n0_) + cc1 * 8, &Vls[buf][(2 * w + 1) * 512]); \
    } while (0)

    ASTAGE(0, 0);
    ASTAGE(1, 64);

    for (int t = 0; t < ntb; ++t) {
        if (t + 1 < ntb) { VMCNT(4); } else { VMCNT(0); }
        BAR();
        SFENCE();
        if (t + 2 < ntb) ASTAGE((t + 2) % 3, (t + 2) * 64);
        const int n0 = t * 64;

        if (n0 < q0w + 32) {
            const short* Kc = Kls[t % 3];
            const short* Vc = Vls[t % 3];

            f32x16 s0 = {0.f,0.f,0.f,0.f,0.f,0.f,0.f,0.f,0.f,0.f,0.f,0.f,0.f,0.f,0.f,0.f};
            f32x16 s1 = s0;
            __builtin_amdgcn_s_setprio(1);
#pragma unroll
            for (int ks = 0; ks < 4; ++ks) {
                bf16x8 kf0 = lds_frag(Kc, l31,      ks * 2 + hi);
                bf16x8 kf1 = lds_frag(Kc, 32 + l31, ks * 2 + hi);
                s0 = __builtin_amdgcn_mfma_f32_32x32x16_bf16(kf0, qf[ks], s0, 0, 0, 0);
                s1 = __builtin_amdgcn_mfma_f32_32x32x16_bf16(kf1, qf[ks], s1, 0, 0, 0);
            }
            __builtin_amdgcn_s_setprio(0);

            float p[32];
#pragma unroll
            for (int r = 0; r < 16; ++r) { p[r] = s0[r]; p[16 + r] = s1[r]; }

            if (n0 + 64 > q0w) {
                const int qrel = q0w + l31 - n0;
#pragma unroll
                for (int r = 0; r < 16; ++r) {
                    const int kvm = (r & 3) + 8 * (r >> 2) + hi4;
                    if (kvm > qrel) p[r] = -3.0e38f;
                    if (kvm + 32 > qrel) p[16 + r] = -3.0e38f;
                }
            }

            float t16[16];
#pragma unroll
            for (int r = 0; r < 16; ++r) t16[r] = fmaxf(p[r], p[16 + r]);
#pragma unroll
            for (int d = 8; d >= 1; d >>= 1)
#pragma unroll
                for (int r = 0; r < 8; ++r)
                    if (r < d) t16[r] = fmaxf(t16[r], t16[r + d]);
            float tmax = fmaxf(t16[0], __shfl_xor(t16[0], 32));

            if (__any(tmax > m + 8.0f)) {
                float mnew = fmaxf(m, tmax);
                float alpha = __builtin_amdgcn_exp2f(m - mnew);
                m = mnew;
#pragma unroll
                for (int r = 0; r < 16; ++r) {
                    float ar = __shfl(alpha, (r & 3) + 8 * (r >> 2) + hi4);
                    o0[r] *= ar; o1[r] *= ar;
                }
                lsum *= alpha;
            }

#pragma unroll
            for (int r = 0; r < 32; ++r) p[r] = __builtin_amdgcn_exp2f(p[r] - m);
            float a16[16];
#pragma unroll
            for (int r = 0; r < 16; ++r) a16[r] = p[r] + p[16 + r];
#pragma unroll
            for (int d = 8; d >= 1; d >>= 1)
#pragma unroll
                for (int r = 0; r < 8; ++r)
                    if (r < d) a16[r] += a16[r + d];
            lsum += a16[0] + __shfl_xor(a16[0], 32);

            __builtin_amdgcn_s_setprio(1);
#pragma unroll
            for (int kb = 0; kb < 2; ++kb) {
                unsigned pk0 = pkbf16(p[kb * 16 + 0],  p[kb * 16 + 1]);
                unsigned pk1 = pkbf16(p[kb * 16 + 2],  p[kb * 16 + 3]);
                unsigned pk2 = pkbf16(p[kb * 16 + 4],  p[kb * 16 + 5]);
                unsigned pk3 = pkbf16(p[kb * 16 + 6],  p[kb * 16 + 7]);
                unsigned pk4 = pkbf16(p[kb * 16 + 8],  p[kb * 16 + 9]);
                unsigned pk5 = pkbf16(p[kb * 16 + 10], p[kb * 16 + 11]);
                unsigned pk6 = pkbf16(p[kb * 16 + 12], p[kb * 16 + 13]);
                unsigned pk7 = pkbf16(p[kb * 16 + 14], p[kb * 16 + 15]);
                pl32swap(pk0, pk2); pl32swap(pk1, pk3);
                pl32swap(pk4, pk6); pl32swap(pk5, pk7);
                U8 f0, f1;
                f0.u[0] = pk0; f0.u[1] = pk1; f0.u[2] = pk2; f0.u[3] = pk3;
                f1.u[0] = pk4; f1.u[1] = pk5; f1.u[2] = pk6; f1.u[3] = pk7;
                bf16x8 v00 = lds_frag(Vc, l31,      kb * 4 + hi);
                bf16x8 v01 = lds_frag(Vc, l31,      kb * 4 + 2 + hi);
                bf16x8 v10 = lds_frag(Vc, 32 + l31, kb * 4 + hi);
                bf16x8 v11 = lds_frag(Vc, 32 + l31, kb * 4 + 2 + hi);
                o0 = __builtin_amdgcn_mfma_f32_32x32x16_bf16(f0.v, v00, o0, 0, 0, 0);
                o0 = __builtin_amdgcn_mfma_f32_32x32x16_bf16(f1.v, v01, o0, 0, 0, 0);
                o1 = __builtin_amdgcn_mfma_f32_32x32x16_bf16(f0.v, v10, o1, 0, 0, 0);
                o1 = __builtin_amdgcn_mfma_f32_32x32x16_bf16(f1.v, v11, o1, 0, 0, 0);
            }
            __builtin_amdgcn_s_setprio(0);
        }
    }
#undef ASTAGE

    const int b = bh >> 4, h = bh & 15;
    const float linv = 1.0f / lsum;
#pragma unroll
    for (int r = 0; r < 16; ++r) {
        const int qoff = (r & 3) + 8 * (r >> 2) + hi4;
        float inv = __shfl(linv, qoff);
        const int mg = b * T_SEQ + q0w + qoff;
        const int mb = mg >> 7, row = mg & 127;
        const int kblk = (l31 >> 3) & 3, el = l & 7;
        Cc[((size_t)(mb * 32 + h * 2 + 0)) * 4096 + kblk * 1024 + row * 8 + el] = f2b(o0[r] * inv);
        Cc[((size_t)(mb * 32 + h * 2 + 1)) * 4096 + kblk * 1024 + row * 8 + el] = f2b(o1[r] * inv);
    }
}

// ---------------- GEMM2: out = concat * W_out^T (fp32 store) ----------------
__global__ __launch_bounds__(256, 3) void gemm_out(const short* __restrict__ ab,
                                                   const short* __restrict__ wb,
                                                   float* __restrict__ out) {
    __shared__ short SM[3][6144];   // [buf][ A:0..4096 | B:4096..6144 ]
    const int tid = threadIdx.x;
    const int w = tid >> 6, l = tid & 63, lg = l >> 4, li = l & 15;
    const int wr = w >> 1, wc = w & 1;
    const int bn = blockIdx.x * 64, bm = blockIdx.y * 128;

    const short* pA = ab + (size_t)blockIdx.y * 32 * 4096 + (w * 128 + l) * 8;
    const short* pB = wb + (size_t)blockIdx.x * 32 * 2048 + (w * 64 + l) * 8;

    f32x4 zero = {0.f, 0.f, 0.f, 0.f};
    f32x4 acc[4][2];
#pragma unroll
    for (int m = 0; m < 4; ++m)
#pragma unroll
        for (int n = 0; n < 2; ++n) acc[m][n] = zero;

#define OSTAGE(buf, t_)                                                  \
    do {                                                                 \
        gll16(pA + (size_t)(t_) * 4096,       &SM[buf][w * 1024]);       \
        gll16(pA + (size_t)(t_) * 4096 + 512, &SM[buf][w * 1024 + 512]); \
        gll16(pB + (size_t)(t_) * 2048,       &SM[buf][4096 + w * 512]); \
    } while (0)

    OSTAGE(0, 0);
    OSTAGE(1, 1);

    for (int t = 0; t < 32; ++t) {
        if (t < 31) { VMCNT(3); } else { VMCNT(0); }
        BAR();
        SFENCE();
        if (t + 2 < 32) OSTAGE((t + 2) % 3, t + 2);
        const short* Ac = &SM[t % 3][0];
        const short* Bc = &SM[t % 3][4096];
        bf16x8 a[4], b[2];
#pragma unroll
        for (int m = 0; m < 4; ++m)
            a[m] = *reinterpret_cast<const bf16x8*>(&Ac[lg * 1024 + (wr * 64 + m * 16 + li) * 8]);
#pragma unroll
        for (int n = 0; n < 2; ++n)
            b[n] = *reinterpret_cast<const bf16x8*>(&Bc[lg * 512 + (wc * 32 + n * 16 + li) * 8]);
        __builtin_amdgcn_s_setprio(1);
#pragma unroll
        for (int m = 0; m < 4; ++m)
#pragma unroll
            for (int n = 0; n < 2; ++n)
                acc[m][n] = __builtin_amdgcn_mfma_f32_16x16x32_bf16(a[m], b[n], acc[m][n], 0, 0, 0);
        __builtin_amdgcn_s_setprio(0);
    }
#undef OSTAGE

#pragma unroll
    for (int m = 0; m < 4; ++m)
#pragma unroll
        for (int n = 0; n < 2; ++n)
#pragma unroll
            for (int r = 0; r < 4; ++r) {
                const int mi = bm + wr * 64 + m * 16 + lg * 4 + r;
                out[(size_t)mi * D_MODEL + bn + wc * 32 + n * 16 + li] = acc[m][n][r];
            }
}

extern "C" void kernel_launch(void* const* d_in, const int* in_sizes, int n_in,
                              void* d_out, int out_size, void* d_ws, size_t ws_size,
                              hipStream_t stream) {
    const float* x    = (const float*)d_in[0];
    const int*   pos  = (const int*)d_in[1];
    const float* wqkv = (const float*)d_in[2];
    const float* wout = (const float*)d_in[3];
    float* out = (float*)d_out;

    char* ws = (char*)d_ws;
    size_t off = 0;
    short* xb  = (short*)(ws + off); off += (size_t)4096 * 1024 * 2;
    short* wqb = (short*)(ws + off); off += (size_t)3072 * 1024 * 2;
    short* wob = (short*)(ws + off); off += (size_t)1024 * 1024 * 2;
    short* Q   = (short*)(ws + off); off += (size_t)32 * 2048 * 64 * 2;
    short* Kb  = (short*)(ws + off); off += (size_t)32 * 2048 * 64 * 2;
    short* Vt  = (short*)(ws + off); off += (size_t)32 * 64 * 2048 * 2;
    off += 4096;
    short* Cc  = (short*)(ws + off); off += (size_t)4096 * 1024 * 2;
    float* ct  = (float*)(ws + off); off += (size_t)4096 * 32 * 4;
    float* st  = (float*)(ws + off); off += (size_t)4096 * 32 * 4;

    cvt_all<<<4608, 256, 0, stream>>>(x, wqkv, wout, pos, xb, wqb, wob, ct, st);
    gemm_qkv<<<dim3(24, 32), 256, 0, stream>>>(xb, wqb, ct, st, Q, Kb, Vt);
    attn<<<512, 256, 0, stream>>>(Q, Kb, Vt, Cc);
    gemm_out<<<dim3(16, 32), 256, 0, stream>>>(Cc, wob, out);
}